// Round 6
// baseline (420.895 us; speedup 1.0000x reference)
//
#include <hip/hip_runtime.h>
#include <stdint.h>

// ---------------- types / helpers ----------------
typedef __attribute__((ext_vector_type(4))) float f32x4;
typedef __attribute__((ext_vector_type(16))) float f32x16;
typedef __attribute__((ext_vector_type(8))) short short8;
typedef __attribute__((ext_vector_type(4))) short short4v;
typedef __attribute__((ext_vector_type(4))) unsigned uint4v;

__device__ __forceinline__ short f2bf(float f) {
  union { float f; uint32_t u; } v; v.f = f;
  uint32_t r = v.u + 0x7FFFu + ((v.u >> 16) & 1u);
  return (short)(r >> 16);
}

__device__ __forceinline__ unsigned cvt_pk_bf16(float lo, float hi) {
  unsigned r;
  asm("v_cvt_pk_bf16_f32 %0, %1, %2" : "=v"(r) : "v"(lo), "v"(hi));
  return r;
}

__device__ __forceinline__ f32x4 mfma16(short8 a, short8 b, f32x4 c) {
  return __builtin_amdgcn_mfma_f32_16x16x32_bf16(a, b, c, 0, 0, 0);
}
__device__ __forceinline__ f32x16 mfma32(short8 a, short8 b, f32x16 c) {
  return __builtin_amdgcn_mfma_f32_32x32x16_bf16(a, b, c, 0, 0, 0);
}

#define NB 8
#define LQ 2048
#define LKV 4096
#define DQ 256
#define FF 1024
#define NCHUNK 4
#define ROWS (NB * LQ)   // 16384

#define AS1(p) ((const __attribute__((address_space(1))) void*)(p))
#define AS3(p) ((__attribute__((address_space(3))) void*)(p))

// ---------------- weight transpose + bf16 cast: out[C][R] = in[R][C] ----------------
__global__ void transpose_cast(const float* __restrict__ in, short* __restrict__ out, int R, int C) {
  __shared__ float t[32][33];
  int c0 = blockIdx.x * 32, r0 = blockIdx.y * 32;
  int tx = threadIdx.x, ty = threadIdx.y;  // 32 x 8
#pragma unroll
  for (int dy = 0; dy < 32; dy += 8)
    t[ty + dy][tx] = in[(long)(r0 + ty + dy) * C + c0 + tx];
  __syncthreads();
#pragma unroll
  for (int dy = 0; dy < 32; dy += 8)
    out[(long)(c0 + ty + dy) * R + r0 + tx] = f2bf(t[tx][ty + dy]);
}

// ---------------- staged tile load: [128 rows][64 k] bf16, XOR-swizzled ----------------
template <bool SRCF32>
__device__ __forceinline__ void stage64(const void* src, int ld, long row0, int k0, char* lds, int tid) {
#pragma unroll
  for (int it = 0; it < 4; ++it) {
    int idx = it * 2048 + tid * 8;
    int r = idx >> 6, c = idx & 63;
    short8 v;
    if (SRCF32) {
      const float* p = (const float*)src + (row0 + r) * (long)ld + k0 + c;
      f32x4 f0 = *(const f32x4*)p;
      f32x4 f1 = *(const f32x4*)(p + 4);
#pragma unroll
      for (int j = 0; j < 4; ++j) { v[j] = f2bf(f0[j]); v[4 + j] = f2bf(f1[j]); }
    } else {
      const short* p = (const short*)src + (row0 + r) * (long)ld + k0 + c;
      v = *(const short8*)p;
    }
    *(short8*)(lds + ((r * 128 + c * 2) ^ ((r & 7) << 4))) = v;
  }
}

// ---------------- generic GEMM: C[M,N] = A[M,K] * B[N,K]^T (+epilogues) ----------------
// EPI: 0 = bf16 out + bias[col]; 1 = bf16 out + bias[row]; 2 = f32 out + bias[col] + resid; 3 = relu bf16 + bias[col]
template <bool AF32, bool BF32, int EPI>
__global__ void __launch_bounds__(256, 2) gemm128(
    const void* __restrict__ A, long sAb, int lda,
    const void* __restrict__ B, long sBb, int ldb,
    const float* __restrict__ bias,
    const float* resid, long sRb,
    void* C, long sCb, int ldc, int K) {
  __shared__ char lds[32768];
  const int tid = threadIdx.x;
  const int bn = blockIdx.x, bm = blockIdx.y, bz = blockIdx.z;
  const void* Ap = AF32 ? (const void*)((const float*)A + sAb * bz) : (const void*)((const short*)A + sAb * bz);
  const void* Bp = BF32 ? (const void*)((const float*)B + sBb * bz) : (const void*)((const short*)B + sBb * bz);
  const int w = tid >> 6, l = tid & 63;
  const int wm = w & 1, wn = w >> 1;
  const int lr = l & 15, lq = l >> 4;
  f32x4 acc[4][4] = {};
  for (int k0 = 0; k0 < K; k0 += 64) {
    stage64<AF32>(Ap, lda, (long)bm * 128, k0, lds, tid);
    stage64<BF32>(Bp, ldb, (long)bn * 128, k0, lds + 16384, tid);
    __syncthreads();
    short8 af[4][2], bfr[4][2];
#pragma unroll
    for (int i = 0; i < 4; ++i) {
#pragma unroll
      for (int kk = 0; kk < 2; ++kk) {
        int ra = wm * 64 + i * 16 + lr;
        af[i][kk] = *(const short8*)(lds + ((ra * 128 + (kk * 32 + lq * 8) * 2) ^ ((ra & 7) << 4)));
        int rb = wn * 64 + i * 16 + lr;
        bfr[i][kk] = *(const short8*)(lds + 16384 + ((rb * 128 + (kk * 32 + lq * 8) * 2) ^ ((rb & 7) << 4)));
      }
    }
#pragma unroll
    for (int i = 0; i < 4; ++i)
#pragma unroll
      for (int j = 0; j < 4; ++j) {
        acc[i][j] = mfma16(af[i][0], bfr[j][0], acc[i][j]);
        acc[i][j] = mfma16(af[i][1], bfr[j][1], acc[i][j]);
      }
    __syncthreads();
  }
#pragma unroll
  for (int i = 0; i < 4; ++i) {
#pragma unroll
    for (int j = 0; j < 4; ++j) {
#pragma unroll
      for (int r = 0; r < 4; ++r) {
        long row = (long)bm * 128 + wm * 64 + i * 16 + lq * 4 + r;
        long col = (long)bn * 128 + wn * 64 + j * 16 + lr;
        float v = acc[i][j][r];
        if (EPI == 0) {
          v += bias[col];
          ((short*)C + sCb * bz)[row * ldc + col] = f2bf(v);
        } else if (EPI == 1) {
          v += bias[row];
          ((short*)C + sCb * bz)[row * ldc + col] = f2bf(v);
        } else if (EPI == 2) {
          v += bias[col] + (resid + sRb * bz)[row * ldc + col];
          ((float*)C + sCb * bz)[row * ldc + col] = v;
        } else {
          v += bias[col];
          v = fmaxf(v, 0.f);
          ((short*)C + sCb * bz)[row * ldc + col] = f2bf(v);
        }
      }
    }
  }
}

// ---------------- flash attention: swapped-QK^T 32x32, 8 waves, gload_lds dbuf ----------------
// grid 256 (1 block/CU): n&7 = batch = XCD slot (per-XCD KV working set = 4MB = L2).
// Block 512 = 8 waves, wave owns 32 q rows (256 q/block); all waves share the KV tile,
// so 2 waves/SIMD overlap softmax-VALU with MFMA. LDS: dbuf 2 x (K 32KB + V^T 32KB) = 128KB.
// Staging: global_load_lds 16B, linear LDS dest, inverse-swizzled global source (involution).
// Q is pre-scaled by 1/sqrt(256)*log2e at bf16 cast -> S comes out in base-2 units.
__global__ void __launch_bounds__(512, 2) flash_attn(
    const float* __restrict__ Q, const short* __restrict__ Kb,
    const short* __restrict__ Vt, float* __restrict__ Opart,
    float* __restrict__ Mb, float* __restrict__ Lb) {
  __shared__ char lds[131072];
  const int tid = threadIdx.x;
  const int n = blockIdx.x;
  const int b = n & 7;           // XCD-local batch
  const int slot = n >> 3;       // [0,32)
  const int qt = slot & 7;
  const int ch = slot >> 3;      // [0,4)
  const int wid = tid >> 6, l = tid & 63;
  const int ql = l & 31, h = l >> 5;
  const int qrow0 = qt * 256 + wid * 32;
  const float* Qp = Q + ((long)b * LQ + qrow0 + ql) * DQ;
  const short* Kp = Kb + (long)b * LKV * DQ;
  const short* Vp = Vt + (long)b * DQ * LKV;
  const float SCQ = 0.0625f * 1.4426950408889634f;  // folded into Q cast

  // async stage tile -> LDS buffer via global_load_lds (no VGPR staging).
  // K LDS byte L(r,cc)=r*512+cc*16 holds global chunk cc^(r&15); V: L(d,cc)=d*128+cc*16 holds cc^(d&7).
  auto stage = [&](int bufb, int kv0) {
    char* kqb = lds + bufb * 65536;
    char* vtb = kqb + 32768;
#pragma unroll
    for (int i = 0; i < 4; ++i) {
      const int j = wid * 4096 + i * 1024;       // wave-uniform LDS span base
      // K: lane covers row r = (j>>9) + (l>>5), chunk cc = l&31
      {
        int r = (j >> 9) + (l >> 5);
        int cc = l & 31;
        const short* gk = Kp + (long)(kv0 + r) * DQ + ((cc ^ (r & 15)) * 8);
        __builtin_amdgcn_global_load_lds(AS1(gk), AS3(kqb + j), 16, 0, 0);
      }
      // V: lane covers row d = (j>>7) + (l>>3), chunk cc = l&7
      {
        int d = (j >> 7) + (l >> 3);
        int cc = l & 7;
        const short* gv = Vp + (long)d * LKV + kv0 + ((cc ^ (d & 7)) * 8);
        __builtin_amdgcn_global_load_lds(AS1(gv), AS3(vtb + j), 16, 0, 0);
      }
    }
  };

  // preload Q fragments (pre-scaled): lane l supplies Q[q=ql][c=16w+8h+j]
  short8 qf[16];
#pragma unroll
  for (int w = 0; w < 16; ++w) {
    const float* p = Qp + w * 16 + h * 8;
    f32x4 f0 = *(const f32x4*)p, f1 = *(const f32x4*)(p + 4);
    short8 v;
#pragma unroll
    for (int j = 0; j < 4; ++j) { v[j] = f2bf(f0[j] * SCQ); v[4 + j] = f2bf(f1[j] * SCQ); }
    qf[w] = v;
  }

  f32x16 o[8] = {};          // O[32q x 256d] accumulator (8 d-tiles of 32)
  float m_r = -1e30f, l_r = 0.f;

  const int kv_lo = ch * (LKV / NCHUNK);
  const int NT = (LKV / NCHUNK) / 64;   // 16 tiles

  stage(0, kv_lo);

  for (int t = 0; t < NT; ++t) {
    if (t + 1 < NT) {
      stage((t + 1) & 1, kv_lo + (t + 1) * 64);
      asm volatile("s_waitcnt vmcnt(8)" ::: "memory");   // tile t landed; t+1's 8 stay in flight
    } else {
      asm volatile("s_waitcnt vmcnt(0)" ::: "memory");
    }
    __builtin_amdgcn_s_barrier();
    __builtin_amdgcn_sched_barrier(0);
    char* kq = lds + (t & 1) * 65536;
    char* vt = kq + 32768;

#pragma unroll
    for (int st = 0; st < 2; ++st) {  // two 32-kv subtiles
      // S^T = K * Q^T : D[kv][q], lane col q=ql, rows (r&3)+8(r>>2)+4h  (base-2 units)
      f32x16 s = {};
      const int krow = 32 * st + ql;
      const int kbase = krow * 512, kswz = (krow & 15) << 4;
      __builtin_amdgcn_s_setprio(1);
#pragma unroll
      for (int w = 0; w < 16; ++w) {
        short8 kf = *(const short8*)(kq + ((kbase + w * 32 + h * 16) ^ kswz));
        s = mfma32(kf, qf[w], s);
      }
      __builtin_amdgcn_s_setprio(0);
      float pmax = s[0];
#pragma unroll
      for (int i = 1; i < 16; ++i) pmax = fmaxf(pmax, s[i]);
      pmax = fmaxf(pmax, __shfl_xor(pmax, 32));
      // defer-max: rescale O only when max grew by > 8 (base-2 units)
      if (__any(pmax > m_r + 8.f)) {
        float mn = fmaxf(m_r, pmax);
        float alpha = exp2f(m_r - mn);
        m_r = mn;
        l_r *= alpha;
#pragma unroll
        for (int rr = 0; rr < 16; ++rr) {
          int src = ((rr & 3) + 8 * (rr >> 2) + 4 * h) + 32 * h;
          float ar = __shfl(alpha, src);
#pragma unroll
          for (int nn = 0; nn < 8; ++nn) o[nn][rr] *= ar;
        }
      }
      // p = exp2(s - m), row-sum, pack to bf16 pairs (v_cvt_pk_bf16_f32)
      float rs = 0.f;
      unsigned wpk[8];
#pragma unroll
      for (int k = 0; k < 8; ++k) {
        float p0 = exp2f(s[2 * k] - m_r);
        float p1 = exp2f(s[2 * k + 1] - m_r);
        rs += p0 + p1;
        wpk[k] = cvt_pk_bf16(p0, p1);
      }
      rs += __shfl_xor(rs, 32);
      l_r += rs;
      // exchange with lane^32 -> PV A-frags pa[v]: A[m=q][k=16v+8h+j] (kv window 32st+16v)
      short8 pa[2];
#pragma unroll
      for (int v = 0; v < 2; ++v) {
        unsigned a0 = wpk[4 * v], a1 = wpk[4 * v + 1];
        unsigned b0 = wpk[4 * v + 2], b1 = wpk[4 * v + 3];
        unsigned own0 = h ? b0 : a0, own1 = h ? b1 : a1;
        unsigned snd0 = h ? a0 : b0, snd1 = h ? a1 : b1;
        unsigned rcv0 = __shfl_xor((int)snd0, 32), rcv1 = __shfl_xor((int)snd1, 32);
        unsigned lo0 = h ? rcv0 : own0, lo1 = h ? rcv1 : own1;
        unsigned hi0 = h ? own0 : rcv0, hi1 = h ? own1 : rcv1;
        uint4v u = {lo0, lo1, hi0, hi1};
        pa[v] = *(short8*)&u;
      }
      // O += P * V' : B-frag from V^T row d=32n+ql, kv bytes 32*(2st+v)+16h
      __builtin_amdgcn_s_setprio(1);
#pragma unroll
      for (int nn = 0; nn < 8; ++nn) {
        const int d = 32 * nn + ql;
        const int dbase = d * 128, dswz = (d & 7) << 4;
#pragma unroll
        for (int v = 0; v < 2; ++v) {
          short8 bv = *(const short8*)(vt + ((dbase + (2 * st + v) * 32 + 16 * h) ^ dswz));
          o[nn] = mfma32(pa[v], bv, o[nn]);
        }
      }
      __builtin_amdgcn_s_setprio(0);
    }
    asm volatile("s_waitcnt lgkmcnt(0)" ::: "memory");  // all LDS reads consumed
    __builtin_amdgcn_s_barrier();                        // buf safe to overwrite next iter
    __builtin_amdgcn_sched_barrier(0);
  }

  // epilogue: unnormalized partial O (f32) + per-row m,l
  const long rowb = (long)b * LQ + qrow0;
#pragma unroll
  for (int rr = 0; rr < 16; ++rr) {
    long grow = rowb + (rr & 3) + 8 * (rr >> 2) + 4 * h;
    float* dst = Opart + ((long)ch * ROWS + grow) * 256 + ql;
#pragma unroll
    for (int nn = 0; nn < 8; ++nn) dst[32 * nn] = o[nn][rr];
  }
  if (h == 0) {
    Mb[(long)ch * ROWS + rowb + ql] = m_r;
    Lb[(long)ch * ROWS + rowb + ql] = l_r;
  }
}

// ---------------- combine KV-split partials -> bf16 context ----------------
__global__ void __launch_bounds__(256) combine_flash(
    const float* __restrict__ Opart, const float* __restrict__ Mb,
    const float* __restrict__ Lb, short* __restrict__ Cb) {
  const int w = threadIdx.x >> 6, l = threadIdx.x & 63;
  const long row = (long)blockIdx.x * 4 + w;
  float mc[NCHUNK];
  float M = -1e30f;
#pragma unroll
  for (int c = 0; c < NCHUNK; ++c) { mc[c] = Mb[(long)c * ROWS + row]; M = fmaxf(M, mc[c]); }
  float L = 0.f;
  float sc[NCHUNK];
#pragma unroll
  for (int c = 0; c < NCHUNK; ++c) { sc[c] = exp2f(mc[c] - M); L += sc[c] * Lb[(long)c * ROWS + row]; }
  float inv = 1.f / L;
  f32x4 o = {0.f, 0.f, 0.f, 0.f};
#pragma unroll
  for (int c = 0; c < NCHUNK; ++c) {
    f32x4 v = *(const f32x4*)(Opart + ((long)c * ROWS + row) * 256 + l * 4);
#pragma unroll
    for (int k = 0; k < 4; ++k) o[k] += sc[c] * v[k];
  }
  short4v y;
#pragma unroll
  for (int k = 0; k < 4; ++k) y[k] = f2bf(o[k] * inv);
  *(short4v*)(Cb + row * 256 + l * 4) = y;
}

// ---------------- layernorm over rows of 256 ----------------
__global__ void __launch_bounds__(256) ln256(
    const float* in, float* outF, short* outB,
    const float* __restrict__ g, const float* __restrict__ be) {
  const int w = threadIdx.x >> 6, l = threadIdx.x & 63;
  const long row = (long)blockIdx.x * 4 + w;
  const float* p = in + row * 256 + l * 4;
  f32x4 x = *(const f32x4*)p;
  float s = x[0] + x[1] + x[2] + x[3];
  float s2 = x[0] * x[0] + x[1] * x[1] + x[2] * x[2] + x[3] * x[3];
#pragma unroll
  for (int mk = 1; mk < 64; mk <<= 1) { s += __shfl_xor(s, mk); s2 += __shfl_xor(s2, mk); }
  float mu = s * (1.f / 256.f);
  float var = s2 * (1.f / 256.f) - mu * mu;
  float rstd = rsqrtf(var + 1e-5f);
  f32x4 gg = *(const f32x4*)(g + l * 4);
  f32x4 bb = *(const f32x4*)(be + l * 4);
  f32x4 y;
#pragma unroll
  for (int k = 0; k < 4; ++k) y[k] = (x[k] - mu) * rstd * gg[k] + bb[k];
  if (outF) *(f32x4*)(outF + row * 256 + l * 4) = y;
  if (outB) {
    short4v yb;
#pragma unroll
    for (int k = 0; k < 4; ++k) yb[k] = f2bf(y[k]);
    *(short4v*)(outB + row * 256 + l * 4) = yb;
  }
}

// ---------------- launcher ----------------
extern "C" void kernel_launch(void* const* d_in, const int* in_sizes, int n_in,
                              void* d_out, int out_size, void* d_ws, size_t ws_size,
                              hipStream_t stream) {
  const float* query = (const float*)d_in[0];
  const float* key   = (const float*)d_in[1];
  const float* value = (const float*)d_in[2];
  const float* Wk  = (const float*)d_in[3];
  const float* bk  = (const float*)d_in[4];
  const float* Wv  = (const float*)d_in[5];
  const float* bv  = (const float*)d_in[6];
  const float* Wo  = (const float*)d_in[7];
  const float* bo  = (const float*)d_in[8];
  const float* g1  = (const float*)d_in[9];
  const float* b1  = (const float*)d_in[10];
  const float* g2  = (const float*)d_in[11];
  const float* b2  = (const float*)d_in[12];
  const float* W1  = (const float*)d_in[13];
  const float* bf1 = (const float*)d_in[14];
  const float* W2  = (const float*)d_in[15];
  const float* bf2 = (const float*)d_in[16];

  char* ws = (char*)d_ws;
  size_t off = 0;
  auto take = [&](size_t bytes) { char* p = ws + off; off += bytes; return p; };
  short* WkT = (short*)take((size_t)256 * 256 * 2);
  short* WvT = (short*)take((size_t)256 * 256 * 2);
  short* WoT = (short*)take((size_t)256 * 256 * 2);
  short* W1T = (short*)take((size_t)1024 * 256 * 2);
  short* W2T = (short*)take((size_t)256 * 1024 * 2);
  short* Kb  = (short*)take((size_t)NB * LKV * DQ * 2);
  short* Vt  = (short*)take((size_t)NB * DQ * LKV * 2);
  short* Cbuf= (short*)take((size_t)NB * LQ * DQ * 2);
  // big region: flash partials, later aliased by Xf/Xb/Hb
  char* big  = take((size_t)NCHUNK * ROWS * 256 * 4 + (size_t)NCHUNK * ROWS * 8);
  float* Opart = (float*)big;
  float* Mbuf  = (float*)(big + (size_t)NCHUNK * ROWS * 256 * 4);
  float* Lbuf  = Mbuf + (size_t)NCHUNK * ROWS;
  float* Xf  = (float*)big;                                      // 16.8MB
  short* Xb  = (short*)(big + (size_t)NB * LQ * DQ * 4);         // 8.4MB
  short* Hb  = (short*)(big + (size_t)NB * LQ * DQ * 6);         // 33.6MB
  (void)ws_size; (void)in_sizes; (void)n_in; (void)out_size;

  dim3 blk(256);
  dim3 tb(32, 8);
  transpose_cast<<<dim3(8, 8),  tb, 0, stream>>>(Wk, WkT, 256, 256);
  transpose_cast<<<dim3(8, 8),  tb, 0, stream>>>(Wv, WvT, 256, 256);
  transpose_cast<<<dim3(8, 8),  tb, 0, stream>>>(Wo, WoT, 256, 256);
  transpose_cast<<<dim3(32, 8), tb, 0, stream>>>(W1, W1T, 256, 1024);
  transpose_cast<<<dim3(8, 32), tb, 0, stream>>>(W2, W2T, 1024, 256);

  // K' = key @ Wk + bk   -> Kb [B*LKV][256] bf16
  gemm128<true, false, 0><<<dim3(2, 256, 1), blk, 0, stream>>>(
      key, 0, 256, WkT, 0, 256, bk, nullptr, 0, Kb, 0, 256, 256);
  // V'^T = (value @ Wv + bv)^T -> Vt [B][256][LKV] bf16  (A = Wv^T, B = value)
  gemm128<false, true, 1><<<dim3(32, 2, 8), blk, 0, stream>>>(
      WvT, 0, 256, value, (long)LKV * 256, 256, bv, nullptr, 0, Vt, (long)256 * LKV, LKV, 256);
  // attention (KV-split 4, swapped-QK^T 32x32, 8-wave blocks, gload_lds dbuf, XCD-pinned)
  flash_attn<<<dim3(256), dim3(512), 0, stream>>>(query, Kb, Vt, Opart, Mbuf, Lbuf);
  combine_flash<<<dim3(ROWS / 4), blk, 0, stream>>>(Opart, Mbuf, Lbuf, Cbuf);
  // attn_out = context @ Wo + bo + query -> Xf f32
  gemm128<false, false, 2><<<dim3(2, 128, 1), blk, 0, stream>>>(
      Cbuf, 0, 256, WoT, 0, 256, bo, query, 0, Xf, 0, 256, 256);
  // x = LN1(Xf) -> Xf (f32, in-place) + Xb (bf16)
  ln256<<<4096, blk, 0, stream>>>(Xf, Xf, Xb, g1, b1);
  // h = relu(x @ W1 + bf1) -> Hb bf16
  gemm128<false, false, 3><<<dim3(8, 128, 1), blk, 0, stream>>>(
      Xb, 0, 256, W1T, 0, 256, bf1, nullptr, 0, Hb, 0, 1024, 256);
  // y = h @ W2 + bf2 + x -> Xf (in-place)
  gemm128<false, false, 2><<<dim3(2, 128, 1), blk, 0, stream>>>(
      Hb, 0, 1024, W2T, 0, 1024, bf2, Xf, 0, Xf, 0, 256, 1024);
  // out = LN2(Xf)
  ln256<<<4096, blk, 0, stream>>>(Xf, (float*)d_out, nullptr, g2, b2);
}

// Round 7
// 419.257 us; speedup vs baseline: 1.0039x; 1.0039x over previous
//
#include <hip/hip_runtime.h>
#include <stdint.h>

// ---------------- types / helpers ----------------
typedef __attribute__((ext_vector_type(4))) float f32x4;
typedef __attribute__((ext_vector_type(16))) float f32x16;
typedef __attribute__((ext_vector_type(8))) short short8;
typedef __attribute__((ext_vector_type(4))) short short4v;
typedef __attribute__((ext_vector_type(4))) unsigned uint4v;

__device__ __forceinline__ short f2bf(float f) {
  union { float f; uint32_t u; } v; v.f = f;
  uint32_t r = v.u + 0x7FFFu + ((v.u >> 16) & 1u);
  return (short)(r >> 16);
}

__device__ __forceinline__ unsigned cvt_pk_bf16(float lo, float hi) {
  unsigned r;
  asm("v_cvt_pk_bf16_f32 %0, %1, %2" : "=v"(r) : "v"(lo), "v"(hi));
  return r;
}

__device__ __forceinline__ f32x4 mfma16(short8 a, short8 b, f32x4 c) {
  return __builtin_amdgcn_mfma_f32_16x16x32_bf16(a, b, c, 0, 0, 0);
}
__device__ __forceinline__ f32x16 mfma32(short8 a, short8 b, f32x16 c) {
  return __builtin_amdgcn_mfma_f32_32x32x16_bf16(a, b, c, 0, 0, 0);
}

#define NB 8
#define LQ 2048
#define LKV 4096
#define DQ 256
#define FF 1024
#define NCHUNK 4
#define ROWS (NB * LQ)   // 16384

#define AS1(p) ((const __attribute__((address_space(1))) void*)(p))
#define AS3(p) ((__attribute__((address_space(3))) void*)(p))

// ---------------- weight transpose + bf16 cast: out[C][R] = in[R][C] ----------------
__global__ void transpose_cast(const float* __restrict__ in, short* __restrict__ out, int R, int C) {
  __shared__ float t[32][33];
  int c0 = blockIdx.x * 32, r0 = blockIdx.y * 32;
  int tx = threadIdx.x, ty = threadIdx.y;  // 32 x 8
#pragma unroll
  for (int dy = 0; dy < 32; dy += 8)
    t[ty + dy][tx] = in[(long)(r0 + ty + dy) * C + c0 + tx];
  __syncthreads();
#pragma unroll
  for (int dy = 0; dy < 32; dy += 8)
    out[(long)(c0 + ty + dy) * R + r0 + tx] = f2bf(t[tx][ty + dy]);
}

// ---------------- staged tile load: [128 rows][64 k] bf16, XOR-swizzled ----------------
template <bool SRCF32>
__device__ __forceinline__ void stage64(const void* src, int ld, long row0, int k0, char* lds, int tid) {
#pragma unroll
  for (int it = 0; it < 4; ++it) {
    int idx = it * 2048 + tid * 8;
    int r = idx >> 6, c = idx & 63;
    short8 v;
    if (SRCF32) {
      const float* p = (const float*)src + (row0 + r) * (long)ld + k0 + c;
      f32x4 f0 = *(const f32x4*)p;
      f32x4 f1 = *(const f32x4*)(p + 4);
#pragma unroll
      for (int j = 0; j < 4; ++j) { v[j] = f2bf(f0[j]); v[4 + j] = f2bf(f1[j]); }
    } else {
      const short* p = (const short*)src + (row0 + r) * (long)ld + k0 + c;
      v = *(const short8*)p;
    }
    *(short8*)(lds + ((r * 128 + c * 2) ^ ((r & 7) << 4))) = v;
  }
}

// ---------------- generic GEMM: C[M,N] = A[M,K] * B[N,K]^T (+epilogues) ----------------
// EPI: 0 = bf16 out + bias[col]; 1 = bf16 out + bias[row]; 2 = f32 out + bias[col] + resid; 3 = relu bf16 + bias[col]
template <bool AF32, bool BF32, int EPI>
__global__ void __launch_bounds__(256, 2) gemm128(
    const void* __restrict__ A, long sAb, int lda,
    const void* __restrict__ B, long sBb, int ldb,
    const float* __restrict__ bias,
    const float* resid, long sRb,
    void* C, long sCb, int ldc, int K) {
  __shared__ char lds[32768];
  const int tid = threadIdx.x;
  const int bn = blockIdx.x, bm = blockIdx.y, bz = blockIdx.z;
  const void* Ap = AF32 ? (const void*)((const float*)A + sAb * bz) : (const void*)((const short*)A + sAb * bz);
  const void* Bp = BF32 ? (const void*)((const float*)B + sBb * bz) : (const void*)((const short*)B + sBb * bz);
  const int w = tid >> 6, l = tid & 63;
  const int wm = w & 1, wn = w >> 1;
  const int lr = l & 15, lq = l >> 4;
  f32x4 acc[4][4] = {};
  for (int k0 = 0; k0 < K; k0 += 64) {
    stage64<AF32>(Ap, lda, (long)bm * 128, k0, lds, tid);
    stage64<BF32>(Bp, ldb, (long)bn * 128, k0, lds + 16384, tid);
    __syncthreads();
    short8 af[4][2], bfr[4][2];
#pragma unroll
    for (int i = 0; i < 4; ++i) {
#pragma unroll
      for (int kk = 0; kk < 2; ++kk) {
        int ra = wm * 64 + i * 16 + lr;
        af[i][kk] = *(const short8*)(lds + ((ra * 128 + (kk * 32 + lq * 8) * 2) ^ ((ra & 7) << 4)));
        int rb = wn * 64 + i * 16 + lr;
        bfr[i][kk] = *(const short8*)(lds + 16384 + ((rb * 128 + (kk * 32 + lq * 8) * 2) ^ ((rb & 7) << 4)));
      }
    }
#pragma unroll
    for (int i = 0; i < 4; ++i)
#pragma unroll
      for (int j = 0; j < 4; ++j) {
        acc[i][j] = mfma16(af[i][0], bfr[j][0], acc[i][j]);
        acc[i][j] = mfma16(af[i][1], bfr[j][1], acc[i][j]);
      }
    __syncthreads();
  }
#pragma unroll
  for (int i = 0; i < 4; ++i) {
#pragma unroll
    for (int j = 0; j < 4; ++j) {
#pragma unroll
      for (int r = 0; r < 4; ++r) {
        long row = (long)bm * 128 + wm * 64 + i * 16 + lq * 4 + r;
        long col = (long)bn * 128 + wn * 64 + j * 16 + lr;
        float v = acc[i][j][r];
        if (EPI == 0) {
          v += bias[col];
          ((short*)C + sCb * bz)[row * ldc + col] = f2bf(v);
        } else if (EPI == 1) {
          v += bias[row];
          ((short*)C + sCb * bz)[row * ldc + col] = f2bf(v);
        } else if (EPI == 2) {
          v += bias[col] + (resid + sRb * bz)[row * ldc + col];
          ((float*)C + sCb * bz)[row * ldc + col] = v;
        } else {
          v += bias[col];
          v = fmaxf(v, 0.f);
          ((short*)C + sCb * bz)[row * ldc + col] = f2bf(v);
        }
      }
    }
  }
}

// ---------------- flash attention: swapped-QK^T 32x32, 8 waves, gload_lds dbuf ----------------
// grid 256 (1 block/CU): n&7 = batch = XCD slot (per-XCD KV working set = 4MB = L2).
// Block 512 = 8 waves, wave owns 32 q rows (256 q/block); all waves share the KV tile,
// 2 waves/SIMD overlap softmax-VALU with MFMA. LDS: dbuf 2 x (K 32KB + V^T 32KB) = 128KB.
// __launch_bounds__(512) ONLY: backend caps VGPR at 256 (launchable), no artificial
// occupancy floor -> no spill (R4/R6 lesson: a tighter cap spills o[] to scratch).
__global__ void __launch_bounds__(512) flash_attn(
    const float* __restrict__ Q, const short* __restrict__ Kb,
    const short* __restrict__ Vt, float* __restrict__ Opart,
    float* __restrict__ Mb, float* __restrict__ Lb) {
  __shared__ char lds[131072];
  const int tid = threadIdx.x;
  const int n = blockIdx.x;
  const int b = n & 7;           // XCD-local batch
  const int slot = n >> 3;       // [0,32)
  const int qt = slot & 7;
  const int ch = slot >> 3;      // [0,4)
  const int wid = tid >> 6, l = tid & 63;
  const int ql = l & 31, h = l >> 5;
  const int qrow0 = qt * 256 + wid * 32;
  const float* Qp = Q + ((long)b * LQ + qrow0 + ql) * DQ;
  const short* Kp = Kb + (long)b * LKV * DQ;
  const short* Vp = Vt + (long)b * DQ * LKV;
  const float SCQ = 0.0625f * 1.4426950408889634f;  // folded into Q cast

  // async stage tile -> LDS buffer via global_load_lds (no VGPR staging).
  // K LDS byte L(r,cc)=r*512+cc*16 holds global chunk cc^(r&15); V: L(d,cc)=d*128+cc*16 holds cc^(d&7).
  auto stage = [&](int bufb, int kv0) {
    char* kqb = lds + bufb * 65536;
    char* vtb = kqb + 32768;
#pragma unroll
    for (int i = 0; i < 4; ++i) {
      const int j = wid * 4096 + i * 1024;       // wave-uniform LDS span base
      // K: lane covers row r = (j>>9) + (l>>5), chunk cc = l&31
      {
        int r = (j >> 9) + (l >> 5);
        int cc = l & 31;
        const short* gk = Kp + (long)(kv0 + r) * DQ + ((cc ^ (r & 15)) * 8);
        __builtin_amdgcn_global_load_lds(AS1(gk), AS3(kqb + j), 16, 0, 0);
      }
      // V: lane covers row d = (j>>7) + (l>>3), chunk cc = l&7
      {
        int d = (j >> 7) + (l >> 3);
        int cc = l & 7;
        const short* gv = Vp + (long)d * LKV + kv0 + ((cc ^ (d & 7)) * 8);
        __builtin_amdgcn_global_load_lds(AS1(gv), AS3(vtb + j), 16, 0, 0);
      }
    }
  };

  // preload Q fragments (pre-scaled): lane l supplies Q[q=ql][c=16w+8h+j]
  short8 qf[16];
#pragma unroll
  for (int w = 0; w < 16; ++w) {
    const float* p = Qp + w * 16 + h * 8;
    f32x4 f0 = *(const f32x4*)p, f1 = *(const f32x4*)(p + 4);
    short8 v;
#pragma unroll
    for (int j = 0; j < 4; ++j) { v[j] = f2bf(f0[j] * SCQ); v[4 + j] = f2bf(f1[j] * SCQ); }
    qf[w] = v;
  }

  f32x16 o[8] = {};          // O[32q x 256d] accumulator (8 d-tiles of 32)
  float m_r = -1e30f, l_r = 0.f;

  const int kv_lo = ch * (LKV / NCHUNK);
  const int NT = (LKV / NCHUNK) / 64;   // 16 tiles

  stage(0, kv_lo);

  for (int t = 0; t < NT; ++t) {
    if (t + 1 < NT) {
      stage((t + 1) & 1, kv_lo + (t + 1) * 64);
      asm volatile("s_waitcnt vmcnt(8)" ::: "memory");   // tile t landed; t+1's 8 stay in flight
    } else {
      asm volatile("s_waitcnt vmcnt(0)" ::: "memory");
    }
    __builtin_amdgcn_s_barrier();
    __builtin_amdgcn_sched_barrier(0);
    char* kq = lds + (t & 1) * 65536;
    char* vt = kq + 32768;

#pragma unroll
    for (int st = 0; st < 2; ++st) {  // two 32-kv subtiles
      // S^T = K * Q^T : D[kv][q], lane col q=ql, rows (r&3)+8(r>>2)+4h  (base-2 units)
      f32x16 s = {};
      const int krow = 32 * st + ql;
      const int kbase = krow * 512, kswz = (krow & 15) << 4;
      __builtin_amdgcn_s_setprio(1);
#pragma unroll
      for (int w = 0; w < 16; ++w) {
        short8 kf = *(const short8*)(kq + ((kbase + w * 32 + h * 16) ^ kswz));
        s = mfma32(kf, qf[w], s);
      }
      __builtin_amdgcn_s_setprio(0);
      float pmax = s[0];
#pragma unroll
      for (int i = 1; i < 16; ++i) pmax = fmaxf(pmax, s[i]);
      pmax = fmaxf(pmax, __shfl_xor(pmax, 32));
      // defer-max: rescale O only when max grew by > 8 (base-2 units)
      if (__any(pmax > m_r + 8.f)) {
        float mn = fmaxf(m_r, pmax);
        float alpha = exp2f(m_r - mn);
        m_r = mn;
        l_r *= alpha;
#pragma unroll
        for (int rr = 0; rr < 16; ++rr) {
          int src = ((rr & 3) + 8 * (rr >> 2) + 4 * h) + 32 * h;
          float ar = __shfl(alpha, src);
#pragma unroll
          for (int nn = 0; nn < 8; ++nn) o[nn][rr] *= ar;
        }
      }
      // p = exp2(s - m), row-sum, pack to bf16 pairs (v_cvt_pk_bf16_f32)
      float rs = 0.f;
      unsigned wpk[8];
#pragma unroll
      for (int k = 0; k < 8; ++k) {
        float p0 = exp2f(s[2 * k] - m_r);
        float p1 = exp2f(s[2 * k + 1] - m_r);
        rs += p0 + p1;
        wpk[k] = cvt_pk_bf16(p0, p1);
      }
      rs += __shfl_xor(rs, 32);
      l_r += rs;
      // exchange with lane^32 -> PV A-frags pa[v]: A[m=q][k=16v+8h+j] (kv window 32st+16v)
      short8 pa[2];
#pragma unroll
      for (int v = 0; v < 2; ++v) {
        unsigned a0 = wpk[4 * v], a1 = wpk[4 * v + 1];
        unsigned b0 = wpk[4 * v + 2], b1 = wpk[4 * v + 3];
        unsigned own0 = h ? b0 : a0, own1 = h ? b1 : a1;
        unsigned snd0 = h ? a0 : b0, snd1 = h ? a1 : b1;
        unsigned rcv0 = __shfl_xor((int)snd0, 32), rcv1 = __shfl_xor((int)snd1, 32);
        unsigned lo0 = h ? rcv0 : own0, lo1 = h ? rcv1 : own1;
        unsigned hi0 = h ? own0 : rcv0, hi1 = h ? own1 : rcv1;
        uint4v u = {lo0, lo1, hi0, hi1};
        pa[v] = *(short8*)&u;
      }
      // O += P * V' : B-frag from V^T row d=32n+ql, kv bytes 32*(2st+v)+16h
      __builtin_amdgcn_s_setprio(1);
#pragma unroll
      for (int nn = 0; nn < 8; ++nn) {
        const int d = 32 * nn + ql;
        const int dbase = d * 128, dswz = (d & 7) << 4;
#pragma unroll
        for (int v = 0; v < 2; ++v) {
          short8 bv = *(const short8*)(vt + ((dbase + (2 * st + v) * 32 + 16 * h) ^ dswz));
          o[nn] = mfma32(pa[v], bv, o[nn]);
        }
      }
      __builtin_amdgcn_s_setprio(0);
    }
    asm volatile("s_waitcnt lgkmcnt(0)" ::: "memory");  // all LDS reads consumed
    __builtin_amdgcn_s_barrier();                        // buf safe to overwrite next iter
    __builtin_amdgcn_sched_barrier(0);
  }

  // epilogue: unnormalized partial O (f32) + per-row m,l
  const long rowb = (long)b * LQ + qrow0;
#pragma unroll
  for (int rr = 0; rr < 16; ++rr) {
    long grow = rowb + (rr & 3) + 8 * (rr >> 2) + 4 * h;
    float* dst = Opart + ((long)ch * ROWS + grow) * 256 + ql;
#pragma unroll
    for (int nn = 0; nn < 8; ++nn) dst[32 * nn] = o[nn][rr];
  }
  if (h == 0) {
    Mb[(long)ch * ROWS + rowb + ql] = m_r;
    Lb[(long)ch * ROWS + rowb + ql] = l_r;
  }
}

// ---------------- combine KV-split partials -> bf16 context ----------------
__global__ void __launch_bounds__(256) combine_flash(
    const float* __restrict__ Opart, const float* __restrict__ Mb,
    const float* __restrict__ Lb, short* __restrict__ Cb) {
  const int w = threadIdx.x >> 6, l = threadIdx.x & 63;
  const long row = (long)blockIdx.x * 4 + w;
  float mc[NCHUNK];
  float M = -1e30f;
#pragma unroll
  for (int c = 0; c < NCHUNK; ++c) { mc[c] = Mb[(long)c * ROWS + row]; M = fmaxf(M, mc[c]); }
  float L = 0.f;
  float sc[NCHUNK];
#pragma unroll
  for (int c = 0; c < NCHUNK; ++c) { sc[c] = exp2f(mc[c] - M); L += sc[c] * Lb[(long)c * ROWS + row]; }
  float inv = 1.f / L;
  f32x4 o = {0.f, 0.f, 0.f, 0.f};
#pragma unroll
  for (int c = 0; c < NCHUNK; ++c) {
    f32x4 v = *(const f32x4*)(Opart + ((long)c * ROWS + row) * 256 + l * 4);
#pragma unroll
    for (int k = 0; k < 4; ++k) o[k] += sc[c] * v[k];
  }
  short4v y;
#pragma unroll
  for (int k = 0; k < 4; ++k) y[k] = f2bf(o[k] * inv);
  *(short4v*)(Cb + row * 256 + l * 4) = y;
}

// ---------------- layernorm over rows of 256 ----------------
__global__ void __launch_bounds__(256) ln256(
    const float* in, float* outF, short* outB,
    const float* __restrict__ g, const float* __restrict__ be) {
  const int w = threadIdx.x >> 6, l = threadIdx.x & 63;
  const long row = (long)blockIdx.x * 4 + w;
  const float* p = in + row * 256 + l * 4;
  f32x4 x = *(const f32x4*)p;
  float s = x[0] + x[1] + x[2] + x[3];
  float s2 = x[0] * x[0] + x[1] * x[1] + x[2] * x[2] + x[3] * x[3];
#pragma unroll
  for (int mk = 1; mk < 64; mk <<= 1) { s += __shfl_xor(s, mk); s2 += __shfl_xor(s2, mk); }
  float mu = s * (1.f / 256.f);
  float var = s2 * (1.f / 256.f) - mu * mu;
  float rstd = rsqrtf(var + 1e-5f);
  f32x4 gg = *(const f32x4*)(g + l * 4);
  f32x4 bb = *(const f32x4*)(be + l * 4);
  f32x4 y;
#pragma unroll
  for (int k = 0; k < 4; ++k) y[k] = (x[k] - mu) * rstd * gg[k] + bb[k];
  if (outF) *(f32x4*)(outF + row * 256 + l * 4) = y;
  if (outB) {
    short4v yb;
#pragma unroll
    for (int k = 0; k < 4; ++k) yb[k] = f2bf(y[k]);
    *(short4v*)(outB + row * 256 + l * 4) = yb;
  }
}

// ---------------- launcher ----------------
extern "C" void kernel_launch(void* const* d_in, const int* in_sizes, int n_in,
                              void* d_out, int out_size, void* d_ws, size_t ws_size,
                              hipStream_t stream) {
  const float* query = (const float*)d_in[0];
  const float* key   = (const float*)d_in[1];
  const float* value = (const float*)d_in[2];
  const float* Wk  = (const float*)d_in[3];
  const float* bk  = (const float*)d_in[4];
  const float* Wv  = (const float*)d_in[5];
  const float* bv  = (const float*)d_in[6];
  const float* Wo  = (const float*)d_in[7];
  const float* bo  = (const float*)d_in[8];
  const float* g1  = (const float*)d_in[9];
  const float* b1  = (const float*)d_in[10];
  const float* g2  = (const float*)d_in[11];
  const float* b2  = (const float*)d_in[12];
  const float* W1  = (const float*)d_in[13];
  const float* bf1 = (const float*)d_in[14];
  const float* W2  = (const float*)d_in[15];
  const float* bf2 = (const float*)d_in[16];

  char* ws = (char*)d_ws;
  size_t off = 0;
  auto take = [&](size_t bytes) { char* p = ws + off; off += bytes; return p; };
  short* WkT = (short*)take((size_t)256 * 256 * 2);
  short* WvT = (short*)take((size_t)256 * 256 * 2);
  short* WoT = (short*)take((size_t)256 * 256 * 2);
  short* W1T = (short*)take((size_t)1024 * 256 * 2);
  short* W2T = (short*)take((size_t)256 * 1024 * 2);
  short* Kb  = (short*)take((size_t)NB * LKV * DQ * 2);
  short* Vt  = (short*)take((size_t)NB * DQ * LKV * 2);
  short* Cbuf= (short*)take((size_t)NB * LQ * DQ * 2);
  // big region: flash partials, later aliased by Xf/Xb/Hb
  char* big  = take((size_t)NCHUNK * ROWS * 256 * 4 + (size_t)NCHUNK * ROWS * 8);
  float* Opart = (float*)big;
  float* Mbuf  = (float*)(big + (size_t)NCHUNK * ROWS * 256 * 4);
  float* Lbuf  = Mbuf + (size_t)NCHUNK * ROWS;
  float* Xf  = (float*)big;                                      // 16.8MB
  short* Xb  = (short*)(big + (size_t)NB * LQ * DQ * 4);         // 8.4MB
  short* Hb  = (short*)(big + (size_t)NB * LQ * DQ * 6);         // 33.6MB
  (void)ws_size; (void)in_sizes; (void)n_in; (void)out_size;

  dim3 blk(256);
  dim3 tb(32, 8);
  transpose_cast<<<dim3(8, 8),  tb, 0, stream>>>(Wk, WkT, 256, 256);
  transpose_cast<<<dim3(8, 8),  tb, 0, stream>>>(Wv, WvT, 256, 256);
  transpose_cast<<<dim3(8, 8),  tb, 0, stream>>>(Wo, WoT, 256, 256);
  transpose_cast<<<dim3(32, 8), tb, 0, stream>>>(W1, W1T, 256, 1024);
  transpose_cast<<<dim3(8, 32), tb, 0, stream>>>(W2, W2T, 1024, 256);

  // K' = key @ Wk + bk   -> Kb [B*LKV][256] bf16
  gemm128<true, false, 0><<<dim3(2, 256, 1), blk, 0, stream>>>(
      key, 0, 256, WkT, 0, 256, bk, nullptr, 0, Kb, 0, 256, 256);
  // V'^T = (value @ Wv + bv)^T -> Vt [B][256][LKV] bf16  (A = Wv^T, B = value)
  gemm128<false, true, 1><<<dim3(32, 2, 8), blk, 0, stream>>>(
      WvT, 0, 256, value, (long)LKV * 256, 256, bv, nullptr, 0, Vt, (long)256 * LKV, LKV, 256);
  // attention (KV-split 4, swapped-QK^T 32x32, 8-wave blocks, gload_lds dbuf, XCD-pinned)
  flash_attn<<<dim3(256), dim3(512), 0, stream>>>(query, Kb, Vt, Opart, Mbuf, Lbuf);
  combine_flash<<<dim3(ROWS / 4), blk, 0, stream>>>(Opart, Mbuf, Lbuf, Cbuf);
  // attn_out = context @ Wo + bo + query -> Xf f32
  gemm128<false, false, 2><<<dim3(2, 128, 1), blk, 0, stream>>>(
      Cbuf, 0, 256, WoT, 0, 256, bo, query, 0, Xf, 0, 256, 256);
  // x = LN1(Xf) -> Xf (f32, in-place) + Xb (bf16)
  ln256<<<4096, blk, 0, stream>>>(Xf, Xf, Xb, g1, b1);
  // h = relu(x @ W1 + bf1) -> Hb bf16
  gemm128<false, false, 3><<<dim3(8, 128, 1), blk, 0, stream>>>(
      Xb, 0, 256, W1T, 0, 256, bf1, nullptr, 0, Hb, 0, 1024, 256);
  // y = h @ W2 + bf2 + x -> Xf (in-place)
  gemm128<false, false, 2><<<dim3(2, 128, 1), blk, 0, stream>>>(
      Hb, 0, 1024, W2T, 0, 1024, bf2, Xf, 0, Xf, 0, 256, 1024);
  // out = LN2(Xf)
  ln256<<<4096, blk, 0, stream>>>(Xf, (float*)d_out, nullptr, g2, b2);
}

// Round 8
// 291.707 us; speedup vs baseline: 1.4429x; 1.4373x over previous
//
#include <hip/hip_runtime.h>
#include <stdint.h>

// ---------------- types / helpers ----------------
typedef __attribute__((ext_vector_type(4))) float f32x4;
typedef __attribute__((ext_vector_type(16))) float f32x16;
typedef __attribute__((ext_vector_type(8))) short short8;
typedef __attribute__((ext_vector_type(4))) short short4v;
typedef __attribute__((ext_vector_type(4))) unsigned uint4v;

__device__ __forceinline__ short f2bf(float f) {
  union { float f; uint32_t u; } v; v.f = f;
  uint32_t r = v.u + 0x7FFFu + ((v.u >> 16) & 1u);
  return (short)(r >> 16);
}

__device__ __forceinline__ unsigned cvt_pk_bf16(float lo, float hi) {
  unsigned r;
  asm("v_cvt_pk_bf16_f32 %0, %1, %2" : "=v"(r) : "v"(lo), "v"(hi));
  return r;
}

__device__ __forceinline__ f32x4 mfma16(short8 a, short8 b, f32x4 c) {
  return __builtin_amdgcn_mfma_f32_16x16x32_bf16(a, b, c, 0, 0, 0);
}
__device__ __forceinline__ f32x16 mfma32(short8 a, short8 b, f32x16 c) {
  return __builtin_amdgcn_mfma_f32_32x32x16_bf16(a, b, c, 0, 0, 0);
}

#define NB 8
#define LQ 2048
#define LKV 4096
#define DQ 256
#define FF 1024
#define NCHUNK 4
#define ROWS (NB * LQ)   // 16384

#define AS1(p) ((const __attribute__((address_space(1))) void*)(p))
#define AS3(p) ((__attribute__((address_space(3))) void*)(p))

// ---------------- weight transpose + bf16 cast: out[C][R] = in[R][C] ----------------
__global__ void transpose_cast(const float* __restrict__ in, short* __restrict__ out, int R, int C) {
  __shared__ float t[32][33];
  int c0 = blockIdx.x * 32, r0 = blockIdx.y * 32;
  int tx = threadIdx.x, ty = threadIdx.y;  // 32 x 8
#pragma unroll
  for (int dy = 0; dy < 32; dy += 8)
    t[ty + dy][tx] = in[(long)(r0 + ty + dy) * C + c0 + tx];
  __syncthreads();
#pragma unroll
  for (int dy = 0; dy < 32; dy += 8)
    out[(long)(c0 + ty + dy) * R + r0 + tx] = f2bf(t[tx][ty + dy]);
}

// ---------------- staged tile load: [128 rows][64 k] bf16, XOR-swizzled ----------------
template <bool SRCF32>
__device__ __forceinline__ void stage64(const void* src, int ld, long row0, int k0, char* lds, int tid) {
#pragma unroll
  for (int it = 0; it < 4; ++it) {
    int idx = it * 2048 + tid * 8;
    int r = idx >> 6, c = idx & 63;
    short8 v;
    if (SRCF32) {
      const float* p = (const float*)src + (row0 + r) * (long)ld + k0 + c;
      f32x4 f0 = *(const f32x4*)p;
      f32x4 f1 = *(const f32x4*)(p + 4);
#pragma unroll
      for (int j = 0; j < 4; ++j) { v[j] = f2bf(f0[j]); v[4 + j] = f2bf(f1[j]); }
    } else {
      const short* p = (const short*)src + (row0 + r) * (long)ld + k0 + c;
      v = *(const short8*)p;
    }
    *(short8*)(lds + ((r * 128 + c * 2) ^ ((r & 7) << 4))) = v;
  }
}

// ---------------- generic GEMM: C[M,N] = A[M,K] * B[N,K]^T (+epilogues) ----------------
// EPI: 0 = bf16 out + bias[col]; 1 = bf16 out + bias[row]; 2 = f32 out + bias[col] + resid; 3 = relu bf16 + bias[col]
template <bool AF32, bool BF32, int EPI>
__global__ void __launch_bounds__(256, 2) gemm128(
    const void* __restrict__ A, long sAb, int lda,
    const void* __restrict__ B, long sBb, int ldb,
    const float* __restrict__ bias,
    const float* resid, long sRb,
    void* C, long sCb, int ldc, int K) {
  __shared__ char lds[32768];
  const int tid = threadIdx.x;
  const int bn = blockIdx.x, bm = blockIdx.y, bz = blockIdx.z;
  const void* Ap = AF32 ? (const void*)((const float*)A + sAb * bz) : (const void*)((const short*)A + sAb * bz);
  const void* Bp = BF32 ? (const void*)((const float*)B + sBb * bz) : (const void*)((const short*)B + sBb * bz);
  const int w = tid >> 6, l = tid & 63;
  const int wm = w & 1, wn = w >> 1;
  const int lr = l & 15, lq = l >> 4;
  f32x4 acc[4][4] = {};
  for (int k0 = 0; k0 < K; k0 += 64) {
    stage64<AF32>(Ap, lda, (long)bm * 128, k0, lds, tid);
    stage64<BF32>(Bp, ldb, (long)bn * 128, k0, lds + 16384, tid);
    __syncthreads();
    short8 af[4][2], bfr[4][2];
#pragma unroll
    for (int i = 0; i < 4; ++i) {
#pragma unroll
      for (int kk = 0; kk < 2; ++kk) {
        int ra = wm * 64 + i * 16 + lr;
        af[i][kk] = *(const short8*)(lds + ((ra * 128 + (kk * 32 + lq * 8) * 2) ^ ((ra & 7) << 4)));
        int rb = wn * 64 + i * 16 + lr;
        bfr[i][kk] = *(const short8*)(lds + 16384 + ((rb * 128 + (kk * 32 + lq * 8) * 2) ^ ((rb & 7) << 4)));
      }
    }
#pragma unroll
    for (int i = 0; i < 4; ++i)
#pragma unroll
      for (int j = 0; j < 4; ++j) {
        acc[i][j] = mfma16(af[i][0], bfr[j][0], acc[i][j]);
        acc[i][j] = mfma16(af[i][1], bfr[j][1], acc[i][j]);
      }
    __syncthreads();
  }
#pragma unroll
  for (int i = 0; i < 4; ++i) {
#pragma unroll
    for (int j = 0; j < 4; ++j) {
#pragma unroll
      for (int r = 0; r < 4; ++r) {
        long row = (long)bm * 128 + wm * 64 + i * 16 + lq * 4 + r;
        long col = (long)bn * 128 + wn * 64 + j * 16 + lr;
        float v = acc[i][j][r];
        if (EPI == 0) {
          v += bias[col];
          ((short*)C + sCb * bz)[row * ldc + col] = f2bf(v);
        } else if (EPI == 1) {
          v += bias[row];
          ((short*)C + sCb * bz)[row * ldc + col] = f2bf(v);
        } else if (EPI == 2) {
          v += bias[col] + (resid + sRb * bz)[row * ldc + col];
          ((float*)C + sCb * bz)[row * ldc + col] = v;
        } else {
          v += bias[col];
          v = fmaxf(v, 0.f);
          ((short*)C + sCb * bz)[row * ldc + col] = f2bf(v);
        }
      }
    }
  }
}

// ---------------- flash attention: swapped-QK^T 32x32, 2 blocks/CU, single-buffer ----------------
// grid 512, 256 threads (4 waves): n&7 = batch = XCD slot (per-XCD KV = 4MB = L2).
// Wave owns 32 q rows (128 q/block). LDS 64KB single buffer -> 2 blocks/CU co-resident
// (2x240 VGPR = 480 <= 512/SIMD, 2x64KB = 128KB <= 160KB). Cross-block TLP hides the
// stage stall that dbuf used to cover. __launch_bounds__(256,1): proven 240-VGPR codegen
// (R4/R6/R7 lesson: any tighter cap spills o[] to scratch -> 2x slower + HBM blowup).
__global__ void __launch_bounds__(256, 1) flash_attn(
    const float* __restrict__ Q, const short* __restrict__ Kb,
    const short* __restrict__ Vt, float* __restrict__ Opart,
    float* __restrict__ Mb, float* __restrict__ Lb) {
  __shared__ char lds[65536];
  char* kq = lds;          // K tile [64 kv][256 d], swz ^((r&15)<<4) on 16B chunks
  char* vt = lds + 32768;  // V^T tile [256 d][64 kv], swz ^((d&7)<<4)
  const int tid = threadIdx.x;
  const int n = blockIdx.x;
  const int b = n & 7;           // XCD-local batch
  const int slot = n >> 3;       // [0,64)
  const int qt = slot & 15;
  const int ch = slot >> 4;      // [0,4)
  const int wid = tid >> 6, l = tid & 63;
  const int ql = l & 31, h = l >> 5;
  const int qrow0 = qt * 128 + wid * 32;
  const float* Qp = Q + ((long)b * LQ + qrow0 + ql) * DQ;
  const short* Kp = Kb + (long)b * LKV * DQ;
  const short* Vp = Vt + (long)b * DQ * LKV;
  const float SCQ = 0.0625f * 1.4426950408889634f;  // folded into Q cast

  // async stage tile via global_load_lds (no VGPR staging): linear LDS dest,
  // inverse-swizzled global source (XOR is an involution within each row).
  auto stage = [&](int kv0) {
#pragma unroll
    for (int i = 0; i < 8; ++i) {
      const int j = wid * 8192 + i * 1024;       // wave-uniform LDS span base
      // K: lane covers row r = (j>>9) + (l>>5), chunk cc = l&31
      {
        int r = (j >> 9) + (l >> 5);
        int cc = l & 31;
        const short* gk = Kp + (long)(kv0 + r) * DQ + ((cc ^ (r & 15)) * 8);
        __builtin_amdgcn_global_load_lds(AS1(gk), AS3(kq + j), 16, 0, 0);
      }
      // V: lane covers row d = (j>>7) + (l>>3), chunk cc = l&7
      {
        int d = (j >> 7) + (l >> 3);
        int cc = l & 7;
        const short* gv = Vp + (long)d * LKV + kv0 + ((cc ^ (d & 7)) * 8);
        __builtin_amdgcn_global_load_lds(AS1(gv), AS3(vt + j), 16, 0, 0);
      }
    }
  };

  // preload Q fragments (pre-scaled): lane l supplies Q[q=ql][c=16w+8h+j]
  short8 qf[16];
#pragma unroll
  for (int w = 0; w < 16; ++w) {
    const float* p = Qp + w * 16 + h * 8;
    f32x4 f0 = *(const f32x4*)p, f1 = *(const f32x4*)(p + 4);
    short8 v;
#pragma unroll
    for (int j = 0; j < 4; ++j) { v[j] = f2bf(f0[j] * SCQ); v[4 + j] = f2bf(f1[j] * SCQ); }
    qf[w] = v;
  }

  f32x16 o[8] = {};          // O[32q x 256d] accumulator (8 d-tiles of 32)
  float m_r = -1e30f, l_r = 0.f;

  const int kv_lo = ch * (LKV / NCHUNK);
  const int NT = (LKV / NCHUNK) / 64;   // 16 tiles

  for (int t = 0; t < NT; ++t) {
    stage(kv_lo + t * 64);
    asm volatile("s_waitcnt vmcnt(0)" ::: "memory");
    __builtin_amdgcn_s_barrier();
    __builtin_amdgcn_sched_barrier(0);

#pragma unroll
    for (int st = 0; st < 2; ++st) {  // two 32-kv subtiles
      // S^T = K * Q^T : D[kv][q], lane col q=ql, rows (r&3)+8(r>>2)+4h  (base-2 units)
      f32x16 s = {};
      const int krow = 32 * st + ql;
      const int kbase = krow * 512, kswz = (krow & 15) << 4;
      __builtin_amdgcn_s_setprio(1);
#pragma unroll
      for (int w = 0; w < 16; ++w) {
        short8 kf = *(const short8*)(kq + ((kbase + w * 32 + h * 16) ^ kswz));
        s = mfma32(kf, qf[w], s);
      }
      __builtin_amdgcn_s_setprio(0);
      float pmax = s[0];
#pragma unroll
      for (int i = 1; i < 16; ++i) pmax = fmaxf(pmax, s[i]);
      pmax = fmaxf(pmax, __shfl_xor(pmax, 32));
      // defer-max: rescale O only when max grew by > 8 (base-2 units)
      if (__any(pmax > m_r + 8.f)) {
        float mn = fmaxf(m_r, pmax);
        float alpha = exp2f(m_r - mn);
        m_r = mn;
        l_r *= alpha;
#pragma unroll
        for (int rr = 0; rr < 16; ++rr) {
          int src = ((rr & 3) + 8 * (rr >> 2) + 4 * h) + 32 * h;
          float ar = __shfl(alpha, src);
#pragma unroll
          for (int nn = 0; nn < 8; ++nn) o[nn][rr] *= ar;
        }
      }
      // p = exp2(s - m), row-sum, pack to bf16 pairs (v_cvt_pk_bf16_f32)
      float rs = 0.f;
      unsigned wpk[8];
#pragma unroll
      for (int k = 0; k < 8; ++k) {
        float p0 = exp2f(s[2 * k] - m_r);
        float p1 = exp2f(s[2 * k + 1] - m_r);
        rs += p0 + p1;
        wpk[k] = cvt_pk_bf16(p0, p1);
      }
      rs += __shfl_xor(rs, 32);
      l_r += rs;
      // exchange with lane^32 -> PV A-frags pa[v]: A[m=q][k=16v+8h+j] (kv window 32st+16v)
      short8 pa[2];
#pragma unroll
      for (int v = 0; v < 2; ++v) {
        unsigned a0 = wpk[4 * v], a1 = wpk[4 * v + 1];
        unsigned b0 = wpk[4 * v + 2], b1 = wpk[4 * v + 3];
        unsigned own0 = h ? b0 : a0, own1 = h ? b1 : a1;
        unsigned snd0 = h ? a0 : b0, snd1 = h ? a1 : b1;
        unsigned rcv0 = __shfl_xor((int)snd0, 32), rcv1 = __shfl_xor((int)snd1, 32);
        unsigned lo0 = h ? rcv0 : own0, lo1 = h ? rcv1 : own1;
        unsigned hi0 = h ? own0 : rcv0, hi1 = h ? own1 : rcv1;
        uint4v u = {lo0, lo1, hi0, hi1};
        pa[v] = *(short8*)&u;
      }
      // O += P * V' : B-frag from V^T row d=32n+ql, kv bytes 32*(2st+v)+16h
      __builtin_amdgcn_s_setprio(1);
#pragma unroll
      for (int nn = 0; nn < 8; ++nn) {
        const int d = 32 * nn + ql;
        const int dbase = d * 128, dswz = (d & 7) << 4;
#pragma unroll
        for (int v = 0; v < 2; ++v) {
          short8 bv = *(const short8*)(vt + ((dbase + (2 * st + v) * 32 + 16 * h) ^ dswz));
          o[nn] = mfma32(pa[v], bv, o[nn]);
        }
      }
      __builtin_amdgcn_s_setprio(0);
    }
    asm volatile("s_waitcnt lgkmcnt(0)" ::: "memory");  // all LDS reads consumed
    __builtin_amdgcn_s_barrier();                        // buf safe to overwrite next iter
    __builtin_amdgcn_sched_barrier(0);
  }

  // epilogue: unnormalized partial O (f32) + per-row m,l
  const long rowb = (long)b * LQ + qrow0;
#pragma unroll
  for (int rr = 0; rr < 16; ++rr) {
    long grow = rowb + (rr & 3) + 8 * (rr >> 2) + 4 * h;
    float* dst = Opart + ((long)ch * ROWS + grow) * 256 + ql;
#pragma unroll
    for (int nn = 0; nn < 8; ++nn) dst[32 * nn] = o[nn][rr];
  }
  if (h == 0) {
    Mb[(long)ch * ROWS + rowb + ql] = m_r;
    Lb[(long)ch * ROWS + rowb + ql] = l_r;
  }
}

// ---------------- combine KV-split partials -> bf16 context ----------------
__global__ void __launch_bounds__(256) combine_flash(
    const float* __restrict__ Opart, const float* __restrict__ Mb,
    const float* __restrict__ Lb, short* __restrict__ Cb) {
  const int w = threadIdx.x >> 6, l = threadIdx.x & 63;
  const long row = (long)blockIdx.x * 4 + w;
  float mc[NCHUNK];
  float M = -1e30f;
#pragma unroll
  for (int c = 0; c < NCHUNK; ++c) { mc[c] = Mb[(long)c * ROWS + row]; M = fmaxf(M, mc[c]); }
  float L = 0.f;
  float sc[NCHUNK];
#pragma unroll
  for (int c = 0; c < NCHUNK; ++c) { sc[c] = exp2f(mc[c] - M); L += sc[c] * Lb[(long)c * ROWS + row]; }
  float inv = 1.f / L;
  f32x4 o = {0.f, 0.f, 0.f, 0.f};
#pragma unroll
  for (int c = 0; c < NCHUNK; ++c) {
    f32x4 v = *(const f32x4*)(Opart + ((long)c * ROWS + row) * 256 + l * 4);
#pragma unroll
    for (int k = 0; k < 4; ++k) o[k] += sc[c] * v[k];
  }
  short4v y;
#pragma unroll
  for (int k = 0; k < 4; ++k) y[k] = f2bf(o[k] * inv);
  *(short4v*)(Cb + row * 256 + l * 4) = y;
}

// ---------------- layernorm over rows of 256 ----------------
__global__ void __launch_bounds__(256) ln256(
    const float* in, float* outF, short* outB,
    const float* __restrict__ g, const float* __restrict__ be) {
  const int w = threadIdx.x >> 6, l = threadIdx.x & 63;
  const long row = (long)blockIdx.x * 4 + w;
  const float* p = in + row * 256 + l * 4;
  f32x4 x = *(const f32x4*)p;
  float s = x[0] + x[1] + x[2] + x[3];
  float s2 = x[0] * x[0] + x[1] * x[1] + x[2] * x[2] + x[3] * x[3];
#pragma unroll
  for (int mk = 1; mk < 64; mk <<= 1) { s += __shfl_xor(s, mk); s2 += __shfl_xor(s2, mk); }
  float mu = s * (1.f / 256.f);
  float var = s2 * (1.f / 256.f) - mu * mu;
  float rstd = rsqrtf(var + 1e-5f);
  f32x4 gg = *(const f32x4*)(g + l * 4);
  f32x4 bb = *(const f32x4*)(be + l * 4);
  f32x4 y;
#pragma unroll
  for (int k = 0; k < 4; ++k) y[k] = (x[k] - mu) * rstd * gg[k] + bb[k];
  if (outF) *(f32x4*)(outF + row * 256 + l * 4) = y;
  if (outB) {
    short4v yb;
#pragma unroll
    for (int k = 0; k < 4; ++k) yb[k] = f2bf(y[k]);
    *(short4v*)(outB + row * 256 + l * 4) = yb;
  }
}

// ---------------- launcher ----------------
extern "C" void kernel_launch(void* const* d_in, const int* in_sizes, int n_in,
                              void* d_out, int out_size, void* d_ws, size_t ws_size,
                              hipStream_t stream) {
  const float* query = (const float*)d_in[0];
  const float* key   = (const float*)d_in[1];
  const float* value = (const float*)d_in[2];
  const float* Wk  = (const float*)d_in[3];
  const float* bk  = (const float*)d_in[4];
  const float* Wv  = (const float*)d_in[5];
  const float* bv  = (const float*)d_in[6];
  const float* Wo  = (const float*)d_in[7];
  const float* bo  = (const float*)d_in[8];
  const float* g1  = (const float*)d_in[9];
  const float* b1  = (const float*)d_in[10];
  const float* g2  = (const float*)d_in[11];
  const float* b2  = (const float*)d_in[12];
  const float* W1  = (const float*)d_in[13];
  const float* bf1 = (const float*)d_in[14];
  const float* W2  = (const float*)d_in[15];
  const float* bf2 = (const float*)d_in[16];

  char* ws = (char*)d_ws;
  size_t off = 0;
  auto take = [&](size_t bytes) { char* p = ws + off; off += bytes; return p; };
  short* WkT = (short*)take((size_t)256 * 256 * 2);
  short* WvT = (short*)take((size_t)256 * 256 * 2);
  short* WoT = (short*)take((size_t)256 * 256 * 2);
  short* W1T = (short*)take((size_t)1024 * 256 * 2);
  short* W2T = (short*)take((size_t)256 * 1024 * 2);
  short* Kb  = (short*)take((size_t)NB * LKV * DQ * 2);
  short* Vt  = (short*)take((size_t)NB * DQ * LKV * 2);
  short* Cbuf= (short*)take((size_t)NB * LQ * DQ * 2);
  // big region: flash partials, later aliased by Xf/Xb/Hb
  char* big  = take((size_t)NCHUNK * ROWS * 256 * 4 + (size_t)NCHUNK * ROWS * 8);
  float* Opart = (float*)big;
  float* Mbuf  = (float*)(big + (size_t)NCHUNK * ROWS * 256 * 4);
  float* Lbuf  = Mbuf + (size_t)NCHUNK * ROWS;
  float* Xf  = (float*)big;                                      // 16.8MB
  short* Xb  = (short*)(big + (size_t)NB * LQ * DQ * 4);         // 8.4MB
  short* Hb  = (short*)(big + (size_t)NB * LQ * DQ * 6);         // 33.6MB
  (void)ws_size; (void)in_sizes; (void)n_in; (void)out_size;

  dim3 blk(256);
  dim3 tb(32, 8);
  transpose_cast<<<dim3(8, 8),  tb, 0, stream>>>(Wk, WkT, 256, 256);
  transpose_cast<<<dim3(8, 8),  tb, 0, stream>>>(Wv, WvT, 256, 256);
  transpose_cast<<<dim3(8, 8),  tb, 0, stream>>>(Wo, WoT, 256, 256);
  transpose_cast<<<dim3(32, 8), tb, 0, stream>>>(W1, W1T, 256, 1024);
  transpose_cast<<<dim3(8, 32), tb, 0, stream>>>(W2, W2T, 1024, 256);

  // K' = key @ Wk + bk   -> Kb [B*LKV][256] bf16
  gemm128<true, false, 0><<<dim3(2, 256, 1), blk, 0, stream>>>(
      key, 0, 256, WkT, 0, 256, bk, nullptr, 0, Kb, 0, 256, 256);
  // V'^T = (value @ Wv + bv)^T -> Vt [B][256][LKV] bf16  (A = Wv^T, B = value)
  gemm128<false, true, 1><<<dim3(32, 2, 8), blk, 0, stream>>>(
      WvT, 0, 256, value, (long)LKV * 256, 256, bv, nullptr, 0, Vt, (long)256 * LKV, LKV, 256);
  // attention (KV-split 4, swapped-QK^T 32x32, 2 blocks/CU, XCD-pinned)
  flash_attn<<<dim3(512), blk, 0, stream>>>(query, Kb, Vt, Opart, Mbuf, Lbuf);
  combine_flash<<<dim3(ROWS / 4), blk, 0, stream>>>(Opart, Mbuf, Lbuf, Cbuf);
  // attn_out = context @ Wo + bo + query -> Xf f32
  gemm128<false, false, 2><<<dim3(2, 128, 1), blk, 0, stream>>>(
      Cbuf, 0, 256, WoT, 0, 256, bo, query, 0, Xf, 0, 256, 256);
  // x = LN1(Xf) -> Xf (f32, in-place) + Xb (bf16)
  ln256<<<4096, blk, 0, stream>>>(Xf, Xf, Xb, g1, b1);
  // h = relu(x @ W1 + bf1) -> Hb bf16
  gemm128<false, false, 3><<<dim3(8, 128, 1), blk, 0, stream>>>(
      Xb, 0, 256, W1T, 0, 256, bf1, nullptr, 0, Hb, 0, 1024, 256);
  // y = h @ W2 + bf2 + x -> Xf (in-place)
  gemm128<false, false, 2><<<dim3(2, 128, 1), blk, 0, stream>>>(
      Hb, 0, 1024, W2T, 0, 1024, bf2, Xf, 0, Xf, 0, 256, 1024);
  // out = LN2(Xf)
  ln256<<<4096, blk, 0, stream>>>(Xf, (float*)d_out, nullptr, g2, b2);
}

// Round 9
// 272.634 us; speedup vs baseline: 1.5438x; 1.0700x over previous
//
#include <hip/hip_runtime.h>
#include <stdint.h>

// ---------------- types / helpers ----------------
typedef __attribute__((ext_vector_type(4))) float f32x4;
typedef __attribute__((ext_vector_type(16))) float f32x16;
typedef __attribute__((ext_vector_type(8))) short short8;
typedef __attribute__((ext_vector_type(4))) short short4v;
typedef __attribute__((ext_vector_type(4))) unsigned uint4v;

__device__ __forceinline__ short f2bf(float f) {
  union { float f; uint32_t u; } v; v.f = f;
  uint32_t r = v.u + 0x7FFFu + ((v.u >> 16) & 1u);
  return (short)(r >> 16);
}

__device__ __forceinline__ unsigned cvt_pk_bf16(float lo, float hi) {
  unsigned r;
  asm("v_cvt_pk_bf16_f32 %0, %1, %2" : "=v"(r) : "v"(lo), "v"(hi));
  return r;
}

__device__ __forceinline__ f32x4 mfma16(short8 a, short8 b, f32x4 c) {
  return __builtin_amdgcn_mfma_f32_16x16x32_bf16(a, b, c, 0, 0, 0);
}
__device__ __forceinline__ f32x16 mfma32(short8 a, short8 b, f32x16 c) {
  return __builtin_amdgcn_mfma_f32_32x32x16_bf16(a, b, c, 0, 0, 0);
}

#define NB 8
#define LQ 2048
#define LKV 4096
#define DQ 256
#define FF 1024
#define NCHUNK 2
#define ROWS (NB * LQ)   // 16384

#define AS1(p) ((const __attribute__((address_space(1))) void*)(p))
#define AS3(p) ((__attribute__((address_space(3))) void*)(p))

// ---------------- weight transpose + bf16 cast: out[C][R] = in[R][C] ----------------
__global__ void transpose_cast(const float* __restrict__ in, short* __restrict__ out, int R, int C) {
  __shared__ float t[32][33];
  int c0 = blockIdx.x * 32, r0 = blockIdx.y * 32;
  int tx = threadIdx.x, ty = threadIdx.y;  // 32 x 8
#pragma unroll
  for (int dy = 0; dy < 32; dy += 8)
    t[ty + dy][tx] = in[(long)(r0 + ty + dy) * C + c0 + tx];
  __syncthreads();
#pragma unroll
  for (int dy = 0; dy < 32; dy += 8)
    out[(long)(c0 + ty + dy) * R + r0 + tx] = f2bf(t[tx][ty + dy]);
}

// ---------------- generic GEMM: C[M,N] = A[M,K] * B[N,K]^T (+epilogues) ----------------
// Tile 128x128, BK=64, 4 waves. LDS layout [128][64] bf16, chunk swizzle c ^= (r&7).
// AMODE/BMODE: 0 = bf16 source via global_load_lds (linear LDS dest, inverse-swizzled
// per-lane global source); 1 = f32 source, reg-staged + cvt_pk; 2 = combine two Opart
// f32 planes with per-row softmax weights (flash KV-split merge), A only.
// EPI: 0 = bf16 + bias[col]; 1 = bf16 + bias[row]; 2 = f32 + bias[col] + resid; 3 = relu bf16 + bias[col]
template <int AMODE, int BMODE, int EPI>
__global__ void __launch_bounds__(256, 2) gemm128(
    const void* __restrict__ A, long sAb, int lda,
    const void* __restrict__ B, long sBb, int ldb,
    const float* __restrict__ bias,
    const float* resid, long sRb,
    const float* __restrict__ Mcomb, const float* __restrict__ Lcomb,
    void* C, long sCb, int ldc, int K) {
  __shared__ char lds[32768];
  const int tid = threadIdx.x;
  const int bn = blockIdx.x, bm = blockIdx.y, bz = blockIdx.z;
  const int w = tid >> 6, l = tid & 63;
  const int wm = w & 1, wn = w >> 1;
  const int lr = l & 15, lq = l >> 4;

  // reg-staged f32 -> bf16 (cvt_pk), swizzled LDS write
  auto stageReg = [&](const float* src, int ld, long row0, int k0, char* ldsb) {
#pragma unroll
    for (int it = 0; it < 4; ++it) {
      int idx = it * 2048 + tid * 8;
      int r = idx >> 6, c = idx & 63;
      const float* p = src + (row0 + r) * (long)ld + k0 + c;
      f32x4 f0 = *(const f32x4*)p, f1 = *(const f32x4*)(p + 4);
      uint4v u;
      u[0] = cvt_pk_bf16(f0[0], f0[1]); u[1] = cvt_pk_bf16(f0[2], f0[3]);
      u[2] = cvt_pk_bf16(f1[0], f1[1]); u[3] = cvt_pk_bf16(f1[2], f1[3]);
      *(short8*)(ldsb + ((r * 128 + c * 2) ^ ((r & 7) << 4))) = *(short8*)&u;
    }
  };
  // bf16 via global_load_lds: linear LDS dest, inverse-swizzled global chunk
  auto stageGld = [&](const short* src, int ld, long row0, int k0, char* ldsb) {
#pragma unroll
    for (int it = 0; it < 4; ++it) {
      const int span = it * 4096 + w * 1024;     // wave-uniform
      int idx = (span >> 4) + l;                 // chunk index
      int r = idx >> 3, c = idx & 7;
      __builtin_amdgcn_global_load_lds(
          AS1(src + (row0 + r) * (long)ld + k0 + ((c ^ (r & 7)) * 8)),
          AS3(ldsb + span), 16, 0, 0);
    }
  };
  // combine: a = w0*O0 + w1*O1 with per-row softmax merge weights
  auto stageComb = [&](const float* O0, long row0, int k0, char* ldsb) {
#pragma unroll
    for (int it = 0; it < 4; ++it) {
      int idx = it * 2048 + tid * 8;
      int r = idx >> 6, c = idx & 63;
      long row = row0 + r;
      float m0 = Mcomb[row], m1 = Mcomb[ROWS + row];
      float l0 = Lcomb[row], l1 = Lcomb[ROWS + row];
      float M = fmaxf(m0, m1);
      float e0 = exp2f(m0 - M), e1 = exp2f(m1 - M);
      float inv = 1.f / (e0 * l0 + e1 * l1);
      float w0 = e0 * inv, w1 = e1 * inv;
      const float* p0 = O0 + row * 256 + k0 + c;
      const float* p1 = p0 + (long)ROWS * 256;
      f32x4 a0 = *(const f32x4*)p0, a1 = *(const f32x4*)(p0 + 4);
      f32x4 b0 = *(const f32x4*)p1, b1 = *(const f32x4*)(p1 + 4);
      uint4v u;
      u[0] = cvt_pk_bf16(w0 * a0[0] + w1 * b0[0], w0 * a0[1] + w1 * b0[1]);
      u[1] = cvt_pk_bf16(w0 * a0[2] + w1 * b0[2], w0 * a0[3] + w1 * b0[3]);
      u[2] = cvt_pk_bf16(w0 * a1[0] + w1 * b1[0], w0 * a1[1] + w1 * b1[1]);
      u[3] = cvt_pk_bf16(w0 * a1[2] + w1 * b1[2], w0 * a1[3] + w1 * b1[3]);
      *(short8*)(ldsb + ((r * 128 + c * 2) ^ ((r & 7) << 4))) = *(short8*)&u;
    }
  };

  f32x4 acc[4][4] = {};
  for (int k0 = 0; k0 < K; k0 += 64) {
    if (AMODE == 0)      stageGld((const short*)A + sAb * bz, lda, (long)bm * 128, k0, lds);
    else if (AMODE == 1) stageReg((const float*)A + sAb * bz, lda, (long)bm * 128, k0, lds);
    else                 stageComb((const float*)A, (long)bm * 128, k0, lds);
    if (BMODE == 0)      stageGld((const short*)B + sBb * bz, ldb, (long)bn * 128, k0, lds + 16384);
    else                 stageReg((const float*)B + sBb * bz, ldb, (long)bn * 128, k0, lds + 16384);
    __syncthreads();   // compiler drains vmcnt+lgkmcnt before barrier
    short8 af[4][2], bfr[4][2];
#pragma unroll
    for (int i = 0; i < 4; ++i) {
#pragma unroll
      for (int kk = 0; kk < 2; ++kk) {
        int ra = wm * 64 + i * 16 + lr;
        af[i][kk] = *(const short8*)(lds + ((ra * 128 + (kk * 32 + lq * 8) * 2) ^ ((ra & 7) << 4)));
        int rb = wn * 64 + i * 16 + lr;
        bfr[i][kk] = *(const short8*)(lds + 16384 + ((rb * 128 + (kk * 32 + lq * 8) * 2) ^ ((rb & 7) << 4)));
      }
    }
#pragma unroll
    for (int i = 0; i < 4; ++i)
#pragma unroll
      for (int j = 0; j < 4; ++j) {
        acc[i][j] = mfma16(af[i][0], bfr[j][0], acc[i][j]);
        acc[i][j] = mfma16(af[i][1], bfr[j][1], acc[i][j]);
      }
    __syncthreads();
  }
#pragma unroll
  for (int i = 0; i < 4; ++i) {
#pragma unroll
    for (int j = 0; j < 4; ++j) {
#pragma unroll
      for (int r = 0; r < 4; ++r) {
        long row = (long)bm * 128 + wm * 64 + i * 16 + lq * 4 + r;
        long col = (long)bn * 128 + wn * 64 + j * 16 + lr;
        float v = acc[i][j][r];
        if (EPI == 0) {
          v += bias[col];
          ((short*)C + sCb * bz)[row * ldc + col] = f2bf(v);
        } else if (EPI == 1) {
          v += bias[row];
          ((short*)C + sCb * bz)[row * ldc + col] = f2bf(v);
        } else if (EPI == 2) {
          v += bias[col] + (resid + sRb * bz)[row * ldc + col];
          ((float*)C + sCb * bz)[row * ldc + col] = v;
        } else {
          v += bias[col];
          v = fmaxf(v, 0.f);
          ((short*)C + sCb * bz)[row * ldc + col] = f2bf(v);
        }
      }
    }
  }
}

// ---------------- flash attention: swapped-QK^T 32x32, gload_lds dbuf, counted vmcnt ----------------
// R5-proven structure (142us): grid 256 (1 block/CU), n&7 = batch = XCD slot
// (per-XCD KV = 4MB = L2). Block 256 = 4 waves, wave owns 32 q rows. LDS: 2 buffers x
// (K 32KB + V^T 32KB) = 128KB, counted s_waitcnt vmcnt(16) keeps next tile in flight.
// __launch_bounds__(256,1): proven 240-VGPR no-spill codegen (R4/R6/R7 lesson).
// Q pre-scaled by 1/sqrt(256)*log2e -> S in base-2 units. 1 wave/SIMD (unified
// VGPR+AGPR total > 256 makes 2 waves/SIMD impossible with 32qx256d accumulator).
__global__ void __launch_bounds__(256, 1) flash_attn(
    const float* __restrict__ Q, const short* __restrict__ Kb,
    const short* __restrict__ Vt, float* __restrict__ Opart,
    float* __restrict__ Mb, float* __restrict__ Lb) {
  __shared__ char lds[131072];
  const int tid = threadIdx.x;
  const int n = blockIdx.x;
  const int b = n & 7;           // XCD-local batch
  const int slot = n >> 3;       // [0,32)
  const int qt = slot & 15;
  const int ch = slot >> 4;      // [0,2)
  const int wid = tid >> 6, l = tid & 63;
  const int ql = l & 31, h = l >> 5;
  const int qrow0 = qt * 128 + wid * 32;
  const float* Qp = Q + ((long)b * LQ + qrow0 + ql) * DQ;
  const short* Kp = Kb + (long)b * LKV * DQ;
  const short* Vp = Vt + (long)b * DQ * LKV;
  const float SCQ = 0.0625f * 1.4426950408889634f;  // folded into Q cast

  // async stage tile via global_load_lds: linear LDS dest, inverse-swizzled source.
  auto stage = [&](int bufb, int kv0) {
    char* kqb = lds + bufb * 65536;
    char* vtb = kqb + 32768;
#pragma unroll
    for (int i = 0; i < 8; ++i) {
      const int j = wid * 8192 + i * 1024;       // wave-uniform LDS span base
      {
        int r = (j >> 9) + (l >> 5);
        int cc = l & 31;
        const short* gk = Kp + (long)(kv0 + r) * DQ + ((cc ^ (r & 15)) * 8);
        __builtin_amdgcn_global_load_lds(AS1(gk), AS3(kqb + j), 16, 0, 0);
      }
      {
        int d = (j >> 7) + (l >> 3);
        int cc = l & 7;
        const short* gv = Vp + (long)d * LKV + kv0 + ((cc ^ (d & 7)) * 8);
        __builtin_amdgcn_global_load_lds(AS1(gv), AS3(vtb + j), 16, 0, 0);
      }
    }
  };

  // preload Q fragments (pre-scaled): lane l supplies Q[q=ql][c=16w+8h+j]
  short8 qf[16];
#pragma unroll
  for (int w = 0; w < 16; ++w) {
    const float* p = Qp + w * 16 + h * 8;
    f32x4 f0 = *(const f32x4*)p, f1 = *(const f32x4*)(p + 4);
    short8 v;
#pragma unroll
    for (int j = 0; j < 4; ++j) { v[j] = f2bf(f0[j] * SCQ); v[4 + j] = f2bf(f1[j] * SCQ); }
    qf[w] = v;
  }

  f32x16 o[8] = {};          // O[32q x 256d] accumulator (8 d-tiles of 32)
  float m_r = -1e30f, l_r = 0.f;

  const int kv_lo = ch * (LKV / NCHUNK);
  const int NT = (LKV / NCHUNK) / 64;   // 32 tiles

  stage(0, kv_lo);

  for (int t = 0; t < NT; ++t) {
    if (t + 1 < NT) {
      stage((t + 1) & 1, kv_lo + (t + 1) * 64);
      asm volatile("s_waitcnt vmcnt(16)" ::: "memory");   // tile t landed; t+1's 16 in flight
    } else {
      asm volatile("s_waitcnt vmcnt(0)" ::: "memory");
    }
    __builtin_amdgcn_s_barrier();
    __builtin_amdgcn_sched_barrier(0);
    char* kq = lds + (t & 1) * 65536;
    char* vt = kq + 32768;

#pragma unroll
    for (int st = 0; st < 2; ++st) {  // two 32-kv subtiles
      // S^T = K * Q^T : D[kv][q], lane col q=ql, rows (r&3)+8(r>>2)+4h  (base-2 units)
      f32x16 s = {};
      const int krow = 32 * st + ql;
      const int kbase = krow * 512, kswz = (krow & 15) << 4;
      __builtin_amdgcn_s_setprio(1);
#pragma unroll
      for (int w = 0; w < 16; ++w) {
        short8 kf = *(const short8*)(kq + ((kbase + w * 32 + h * 16) ^ kswz));
        s = mfma32(kf, qf[w], s);
      }
      __builtin_amdgcn_s_setprio(0);
      float pmax = s[0];
#pragma unroll
      for (int i = 1; i < 16; ++i) pmax = fmaxf(pmax, s[i]);
      pmax = fmaxf(pmax, __shfl_xor(pmax, 32));
      // defer-max: rescale O only when max grew by > 8 (base-2 units)
      if (__any(pmax > m_r + 8.f)) {
        float mn = fmaxf(m_r, pmax);
        float alpha = exp2f(m_r - mn);
        m_r = mn;
        l_r *= alpha;
#pragma unroll
        for (int rr = 0; rr < 16; ++rr) {
          int src = ((rr & 3) + 8 * (rr >> 2) + 4 * h) + 32 * h;
          float ar = __shfl(alpha, src);
#pragma unroll
          for (int nn = 0; nn < 8; ++nn) o[nn][rr] *= ar;
        }
      }
      // p = exp2(s - m), row-sum, pack to bf16 pairs
      float rs = 0.f;
      unsigned wpk[8];
#pragma unroll
      for (int k = 0; k < 8; ++k) {
        float p0 = exp2f(s[2 * k] - m_r);
        float p1 = exp2f(s[2 * k + 1] - m_r);
        rs += p0 + p1;
        wpk[k] = cvt_pk_bf16(p0, p1);
      }
      rs += __shfl_xor(rs, 32);
      l_r += rs;
      // exchange with lane^32 -> PV A-frags pa[v]: A[m=q][k=16v+8h+j]
      short8 pa[2];
#pragma unroll
      for (int v = 0; v < 2; ++v) {
        unsigned a0 = wpk[4 * v], a1 = wpk[4 * v + 1];
        unsigned b0 = wpk[4 * v + 2], b1 = wpk[4 * v + 3];
        unsigned own0 = h ? b0 : a0, own1 = h ? b1 : a1;
        unsigned snd0 = h ? a0 : b0, snd1 = h ? a1 : b1;
        unsigned rcv0 = __shfl_xor((int)snd0, 32), rcv1 = __shfl_xor((int)snd1, 32);
        unsigned lo0 = h ? rcv0 : own0, lo1 = h ? rcv1 : own1;
        unsigned hi0 = h ? own0 : rcv0, hi1 = h ? own1 : rcv1;
        uint4v u = {lo0, lo1, hi0, hi1};
        pa[v] = *(short8*)&u;
      }
      // O += P * V' : B-frag from V^T row d=32n+ql, kv bytes 32*(2st+v)+16h
      __builtin_amdgcn_s_setprio(1);
#pragma unroll
      for (int nn = 0; nn < 8; ++nn) {
        const int d = 32 * nn + ql;
        const int dbase = d * 128, dswz = (d & 7) << 4;
#pragma unroll
        for (int v = 0; v < 2; ++v) {
          short8 bv = *(const short8*)(vt + ((dbase + (2 * st + v) * 32 + 16 * h) ^ dswz));
          o[nn] = mfma32(pa[v], bv, o[nn]);
        }
      }
      __builtin_amdgcn_s_setprio(0);
    }
    asm volatile("s_waitcnt lgkmcnt(0)" ::: "memory");  // all LDS reads consumed
    __builtin_amdgcn_s_barrier();                        // buf safe to overwrite next iter
    __builtin_amdgcn_sched_barrier(0);
  }

  // epilogue: unnormalized partial O (f32) + per-row m,l
  const long rowb = (long)b * LQ + qrow0;
#pragma unroll
  for (int rr = 0; rr < 16; ++rr) {
    long grow = rowb + (rr & 3) + 8 * (rr >> 2) + 4 * h;
    float* dst = Opart + ((long)ch * ROWS + grow) * 256 + ql;
#pragma unroll
    for (int nn = 0; nn < 8; ++nn) dst[32 * nn] = o[nn][rr];
  }
  if (h == 0) {
    Mb[(long)ch * ROWS + rowb + ql] = m_r;
    Lb[(long)ch * ROWS + rowb + ql] = l_r;
  }
}

// ---------------- layernorm over rows of 256 ----------------
__global__ void __launch_bounds__(256) ln256(
    const float* in, float* outF, short* outB,
    const float* __restrict__ g, const float* __restrict__ be) {
  const int w = threadIdx.x >> 6, l = threadIdx.x & 63;
  const long row = (long)blockIdx.x * 4 + w;
  const float* p = in + row * 256 + l * 4;
  f32x4 x = *(const f32x4*)p;
  float s = x[0] + x[1] + x[2] + x[3];
  float s2 = x[0] * x[0] + x[1] * x[1] + x[2] * x[2] + x[3] * x[3];
#pragma unroll
  for (int mk = 1; mk < 64; mk <<= 1) { s += __shfl_xor(s, mk); s2 += __shfl_xor(s2, mk); }
  float mu = s * (1.f / 256.f);
  float var = s2 * (1.f / 256.f) - mu * mu;
  float rstd = rsqrtf(var + 1e-5f);
  f32x4 gg = *(const f32x4*)(g + l * 4);
  f32x4 bb = *(const f32x4*)(be + l * 4);
  f32x4 y;
#pragma unroll
  for (int k = 0; k < 4; ++k) y[k] = (x[k] - mu) * rstd * gg[k] + bb[k];
  if (outF) *(f32x4*)(outF + row * 256 + l * 4) = y;
  if (outB) {
    short4v yb;
#pragma unroll
    for (int k = 0; k < 4; ++k) yb[k] = f2bf(y[k]);
    *(short4v*)(outB + row * 256 + l * 4) = yb;
  }
}

// ---------------- launcher ----------------
extern "C" void kernel_launch(void* const* d_in, const int* in_sizes, int n_in,
                              void* d_out, int out_size, void* d_ws, size_t ws_size,
                              hipStream_t stream) {
  const float* query = (const float*)d_in[0];
  const float* key   = (const float*)d_in[1];
  const float* value = (const float*)d_in[2];
  const float* Wk  = (const float*)d_in[3];
  const float* bk  = (const float*)d_in[4];
  const float* Wv  = (const float*)d_in[5];
  const float* bv  = (const float*)d_in[6];
  const float* Wo  = (const float*)d_in[7];
  const float* bo  = (const float*)d_in[8];
  const float* g1  = (const float*)d_in[9];
  const float* b1  = (const float*)d_in[10];
  const float* g2  = (const float*)d_in[11];
  const float* b2  = (const float*)d_in[12];
  const float* W1  = (const float*)d_in[13];
  const float* bf1 = (const float*)d_in[14];
  const float* W2  = (const float*)d_in[15];
  const float* bf2 = (const float*)d_in[16];

  char* ws = (char*)d_ws;
  size_t off = 0;
  auto take = [&](size_t bytes) { char* p = ws + off; off += bytes; return p; };
  short* WkT = (short*)take((size_t)256 * 256 * 2);
  short* WvT = (short*)take((size_t)256 * 256 * 2);
  short* WoT = (short*)take((size_t)256 * 256 * 2);
  short* W1T = (short*)take((size_t)1024 * 256 * 2);
  short* W2T = (short*)take((size_t)256 * 1024 * 2);
  short* Kb  = (short*)take((size_t)NB * LKV * DQ * 2);   // dead after flash -> Hb aliases
  short* Vt  = (short*)take((size_t)NB * DQ * LKV * 2);
  float* Opart = (float*)take((size_t)NCHUNK * ROWS * 256 * 4);  // dead after Wo -> Xb aliases
  float* Mbuf  = (float*)take((size_t)NCHUNK * ROWS * 4);
  float* Lbuf  = (float*)take((size_t)NCHUNK * ROWS * 4);
  float* Xf    = (float*)take((size_t)ROWS * 256 * 4);
  short* Xb  = (short*)Opart;            // LN1 bf16 out (Opart dead)
  short* Hb  = (short*)Kb;               // FF1 out 33.6MB = Kb+Vt region (dead)
  (void)ws_size; (void)in_sizes; (void)n_in; (void)out_size;

  dim3 blk(256);
  dim3 tb(32, 8);
  transpose_cast<<<dim3(8, 8),  tb, 0, stream>>>(Wk, WkT, 256, 256);
  transpose_cast<<<dim3(8, 8),  tb, 0, stream>>>(Wv, WvT, 256, 256);
  transpose_cast<<<dim3(8, 8),  tb, 0, stream>>>(Wo, WoT, 256, 256);
  transpose_cast<<<dim3(32, 8), tb, 0, stream>>>(W1, W1T, 256, 1024);
  transpose_cast<<<dim3(8, 32), tb, 0, stream>>>(W2, W2T, 1024, 256);

  // K' = key @ Wk + bk   -> Kb [B*LKV][256] bf16   (A: f32 reg, B: bf16 gload)
  gemm128<1, 0, 0><<<dim3(2, 256, 1), blk, 0, stream>>>(
      key, 0, 256, WkT, 0, 256, bk, nullptr, 0, nullptr, nullptr, Kb, 0, 256, 256);
  // V'^T = (value @ Wv + bv)^T -> Vt [B][256][LKV] bf16  (A = WvT gload, B = value f32)
  gemm128<0, 1, 1><<<dim3(32, 2, 8), blk, 0, stream>>>(
      WvT, 0, 256, value, (long)LKV * 256, 256, bv, nullptr, 0, nullptr, nullptr,
      Vt, (long)256 * LKV, LKV, 256);
  // attention (KV-split 2, swapped-QK^T 32x32, dbuf + counted vmcnt, XCD-pinned)
  flash_attn<<<dim3(256), blk, 0, stream>>>(query, Kb, Vt, Opart, Mbuf, Lbuf);
  // attn_out = combine(Opart) @ Wo + bo + query -> Xf f32   (combine fused in A-stage)
  gemm128<2, 0, 2><<<dim3(2, 128, 1), blk, 0, stream>>>(
      Opart, 0, 256, WoT, 0, 256, bo, query, 0, Mbuf, Lbuf, Xf, 0, 256, 256);
  // x = LN1(Xf) -> Xf (f32, in-place) + Xb (bf16)
  ln256<<<4096, blk, 0, stream>>>(Xf, Xf, Xb, g1, b1);
  // h = relu(x @ W1 + bf1) -> Hb bf16  (both operands gload)
  gemm128<0, 0, 3><<<dim3(8, 128, 1), blk, 0, stream>>>(
      Xb, 0, 256, W1T, 0, 256, bf1, nullptr, 0, nullptr, nullptr, Hb, 0, 1024, 256);
  // y = h @ W2 + bf2 + x -> Xf (in-place)
  gemm128<0, 0, 2><<<dim3(2, 128, 1), blk, 0, stream>>>(
      Hb, 0, 1024, W2T, 0, 1024, bf2, Xf, 0, nullptr, nullptr, Xf, 0, 256, 1024);
  // out = LN2(Xf)
  ln256<<<4096, blk, 0, stream>>>(Xf, (float*)d_out, nullptr, g2, b2);
}

// Round 10
// 262.164 us; speedup vs baseline: 1.6055x; 1.0399x over previous
//
#include <hip/hip_runtime.h>
#include <stdint.h>

// ---------------- types / helpers ----------------
typedef __attribute__((ext_vector_type(4))) float f32x4;
typedef __attribute__((ext_vector_type(16))) float f32x16;
typedef __attribute__((ext_vector_type(8))) short short8;
typedef __attribute__((ext_vector_type(4))) short short4v;
typedef __attribute__((ext_vector_type(4))) unsigned uint4v;

__device__ __forceinline__ short f2bf(float f) {
  union { float f; uint32_t u; } v; v.f = f;
  uint32_t r = v.u + 0x7FFFu + ((v.u >> 16) & 1u);
  return (short)(r >> 16);
}

__device__ __forceinline__ unsigned cvt_pk_bf16(float lo, float hi) {
  unsigned r;
  asm("v_cvt_pk_bf16_f32 %0, %1, %2" : "=v"(r) : "v"(lo), "v"(hi));
  return r;
}

__device__ __forceinline__ f32x4 mfma16(short8 a, short8 b, f32x4 c) {
  return __builtin_amdgcn_mfma_f32_16x16x32_bf16(a, b, c, 0, 0, 0);
}
__device__ __forceinline__ f32x16 mfma32(short8 a, short8 b, f32x16 c) {
  return __builtin_amdgcn_mfma_f32_32x32x16_bf16(a, b, c, 0, 0, 0);
}

#define NB 8
#define LQ 2048
#define LKV 4096
#define DQ 256
#define FF 1024
#define NCHUNK 2
#define ROWS (NB * LQ)   // 16384

#define AS1(p) ((const __attribute__((address_space(1))) void*)(p))
#define AS3(p) ((__attribute__((address_space(3))) void*)(p))

// ---------------- weight transpose + bf16 cast: out[C][R] = in[R][C] ----------------
__global__ void transpose_cast(const float* __restrict__ in, short* __restrict__ out, int R, int C) {
  __shared__ float t[32][33];
  int c0 = blockIdx.x * 32, r0 = blockIdx.y * 32;
  int tx = threadIdx.x, ty = threadIdx.y;  // 32 x 8
#pragma unroll
  for (int dy = 0; dy < 32; dy += 8)
    t[ty + dy][tx] = in[(long)(r0 + ty + dy) * C + c0 + tx];
  __syncthreads();
#pragma unroll
  for (int dy = 0; dy < 32; dy += 8)
    out[(long)(c0 + ty + dy) * R + r0 + tx] = f2bf(t[tx][ty + dy]);
}

// ---------------- generic GEMM: C[M,N] = A[M,K] * B[N,K]^T (+epilogues) ----------------
// Tile 128x128, BK=64, 4 waves. LDS layout [128][64] bf16, chunk swizzle c ^= (r&7).
// AMODE/BMODE: 0 = bf16 source via global_load_lds (linear LDS dest, inverse-swizzled
// per-lane global source); 1 = f32 source, reg-staged + cvt_pk; 2 = combine two Opart
// f32 planes with per-row softmax weights (flash KV-split merge), A only.
// EPI: 0 = bf16 + bias[col]; 1 = bf16 + bias[row]; 2 = f32 + bias[col] + resid; 3 = relu bf16 + bias[col]
template <int AMODE, int BMODE, int EPI>
__global__ void __launch_bounds__(256, 2) gemm128(
    const void* __restrict__ A, long sAb, int lda,
    const void* __restrict__ B, long sBb, int ldb,
    const float* __restrict__ bias,
    const float* resid, long sRb,
    const float* __restrict__ Mcomb, const float* __restrict__ Lcomb,
    void* C, long sCb, int ldc, int K) {
  __shared__ char lds[32768];
  const int tid = threadIdx.x;
  const int bn = blockIdx.x, bm = blockIdx.y, bz = blockIdx.z;
  const int w = tid >> 6, l = tid & 63;
  const int wm = w & 1, wn = w >> 1;
  const int lr = l & 15, lq = l >> 4;

  // reg-staged f32 -> bf16 (cvt_pk), swizzled LDS write
  auto stageReg = [&](const float* src, int ld, long row0, int k0, char* ldsb) {
#pragma unroll
    for (int it = 0; it < 4; ++it) {
      int idx = it * 2048 + tid * 8;
      int r = idx >> 6, c = idx & 63;
      const float* p = src + (row0 + r) * (long)ld + k0 + c;
      f32x4 f0 = *(const f32x4*)p, f1 = *(const f32x4*)(p + 4);
      uint4v u;
      u[0] = cvt_pk_bf16(f0[0], f0[1]); u[1] = cvt_pk_bf16(f0[2], f0[3]);
      u[2] = cvt_pk_bf16(f1[0], f1[1]); u[3] = cvt_pk_bf16(f1[2], f1[3]);
      *(short8*)(ldsb + ((r * 128 + c * 2) ^ ((r & 7) << 4))) = *(short8*)&u;
    }
  };
  // bf16 via global_load_lds: linear LDS dest, inverse-swizzled global chunk
  auto stageGld = [&](const short* src, int ld, long row0, int k0, char* ldsb) {
#pragma unroll
    for (int it = 0; it < 4; ++it) {
      const int span = it * 4096 + w * 1024;     // wave-uniform
      int idx = (span >> 4) + l;                 // chunk index
      int r = idx >> 3, c = idx & 7;
      __builtin_amdgcn_global_load_lds(
          AS1(src + (row0 + r) * (long)ld + k0 + ((c ^ (r & 7)) * 8)),
          AS3(ldsb + span), 16, 0, 0);
    }
  };
  // combine: a = w0*O0 + w1*O1 with per-row softmax merge weights
  auto stageComb = [&](const float* O0, long row0, int k0, char* ldsb) {
#pragma unroll
    for (int it = 0; it < 4; ++it) {
      int idx = it * 2048 + tid * 8;
      int r = idx >> 6, c = idx & 63;
      long row = row0 + r;
      float m0 = Mcomb[row], m1 = Mcomb[ROWS + row];
      float l0 = Lcomb[row], l1 = Lcomb[ROWS + row];
      float M = fmaxf(m0, m1);
      float e0 = exp2f(m0 - M), e1 = exp2f(m1 - M);
      float inv = 1.f / (e0 * l0 + e1 * l1);
      float w0 = e0 * inv, w1 = e1 * inv;
      const float* p0 = O0 + row * 256 + k0 + c;
      const float* p1 = p0 + (long)ROWS * 256;
      f32x4 a0 = *(const f32x4*)p0, a1 = *(const f32x4*)(p0 + 4);
      f32x4 b0 = *(const f32x4*)p1, b1 = *(const f32x4*)(p1 + 4);
      uint4v u;
      u[0] = cvt_pk_bf16(w0 * a0[0] + w1 * b0[0], w0 * a0[1] + w1 * b0[1]);
      u[1] = cvt_pk_bf16(w0 * a0[2] + w1 * b0[2], w0 * a0[3] + w1 * b0[3]);
      u[2] = cvt_pk_bf16(w0 * a1[0] + w1 * b1[0], w0 * a1[1] + w1 * b1[1]);
      u[3] = cvt_pk_bf16(w0 * a1[2] + w1 * b1[2], w0 * a1[3] + w1 * b1[3]);
      *(short8*)(ldsb + ((r * 128 + c * 2) ^ ((r & 7) << 4))) = *(short8*)&u;
    }
  };

  f32x4 acc[4][4] = {};
  for (int k0 = 0; k0 < K; k0 += 64) {
    if (AMODE == 0)      stageGld((const short*)A + sAb * bz, lda, (long)bm * 128, k0, lds);
    else if (AMODE == 1) stageReg((const float*)A + sAb * bz, lda, (long)bm * 128, k0, lds);
    else                 stageComb((const float*)A, (long)bm * 128, k0, lds);
    if (BMODE == 0)      stageGld((const short*)B + sBb * bz, ldb, (long)bn * 128, k0, lds + 16384);
    else                 stageReg((const float*)B + sBb * bz, ldb, (long)bn * 128, k0, lds + 16384);
    __syncthreads();   // compiler drains vmcnt+lgkmcnt before barrier
    short8 af[4][2], bfr[4][2];
#pragma unroll
    for (int i = 0; i < 4; ++i) {
#pragma unroll
      for (int kk = 0; kk < 2; ++kk) {
        int ra = wm * 64 + i * 16 + lr;
        af[i][kk] = *(const short8*)(lds + ((ra * 128 + (kk * 32 + lq * 8) * 2) ^ ((ra & 7) << 4)));
        int rb = wn * 64 + i * 16 + lr;
        bfr[i][kk] = *(const short8*)(lds + 16384 + ((rb * 128 + (kk * 32 + lq * 8) * 2) ^ ((rb & 7) << 4)));
      }
    }
#pragma unroll
    for (int i = 0; i < 4; ++i)
#pragma unroll
      for (int j = 0; j < 4; ++j) {
        acc[i][j] = mfma16(af[i][0], bfr[j][0], acc[i][j]);
        acc[i][j] = mfma16(af[i][1], bfr[j][1], acc[i][j]);
      }
    __syncthreads();
  }
#pragma unroll
  for (int i = 0; i < 4; ++i) {
#pragma unroll
    for (int j = 0; j < 4; ++j) {
#pragma unroll
      for (int r = 0; r < 4; ++r) {
        long row = (long)bm * 128 + wm * 64 + i * 16 + lq * 4 + r;
        long col = (long)bn * 128 + wn * 64 + j * 16 + lr;
        float v = acc[i][j][r];
        if (EPI == 0) {
          v += bias[col];
          ((short*)C + sCb * bz)[row * ldc + col] = f2bf(v);
        } else if (EPI == 1) {
          v += bias[row];
          ((short*)C + sCb * bz)[row * ldc + col] = f2bf(v);
        } else if (EPI == 2) {
          v += bias[col] + (resid + sRb * bz)[row * ldc + col];
          ((float*)C + sCb * bz)[row * ldc + col] = v;
        } else {
          v += bias[col];
          v = fmaxf(v, 0.f);
          ((short*)C + sCb * bz)[row * ldc + col] = f2bf(v);
        }
      }
    }
  }
}

// ---------------- flash attention: swapped-QK^T 32x32, batched subtiles, dbuf ----------------
// grid 256 (1 block/CU), n&7 = batch = XCD slot (per-XCD KV = 4MB = L2). Block 256 =
// 4 waves, wave owns 32 q rows. LDS: 2 x (K 32KB + V^T 32KB) = 128KB, counted vmcnt(16).
// 1 wave/SIMD (register-bound) -> all parallelism must be ILP: both 32-kv subtiles'
// QK chains run interleaved (2 independent MFMA chains), one tree-max + one deferred
// rescale per tile, PV as 8x4-deep chains. No setprio (nothing to arbitrate at 1 w/SIMD).
__global__ void __launch_bounds__(256, 1) flash_attn(
    const float* __restrict__ Q, const short* __restrict__ Kb,
    const short* __restrict__ Vt, float* __restrict__ Opart,
    float* __restrict__ Mb, float* __restrict__ Lb) {
  __shared__ char lds[131072];
  const int tid = threadIdx.x;
  const int n = blockIdx.x;
  const int b = n & 7;           // XCD-local batch
  const int slot = n >> 3;       // [0,32)
  const int qt = slot & 15;
  const int ch = slot >> 4;      // [0,2)
  const int wid = tid >> 6, l = tid & 63;
  const int ql = l & 31, h = l >> 5;
  const int qrow0 = qt * 128 + wid * 32;
  const float* Qp = Q + ((long)b * LQ + qrow0 + ql) * DQ;
  const short* Kp = Kb + (long)b * LKV * DQ;
  const short* Vp = Vt + (long)b * DQ * LKV;
  const float SCQ = 0.0625f * 1.4426950408889634f;  // folded into Q cast

  // async stage tile via global_load_lds: linear LDS dest, inverse-swizzled source.
  auto stage = [&](int bufb, int kv0) {
    char* kqb = lds + bufb * 65536;
    char* vtb = kqb + 32768;
#pragma unroll
    for (int i = 0; i < 8; ++i) {
      const int j = wid * 8192 + i * 1024;       // wave-uniform LDS span base
      {
        int r = (j >> 9) + (l >> 5);
        int cc = l & 31;
        const short* gk = Kp + (long)(kv0 + r) * DQ + ((cc ^ (r & 15)) * 8);
        __builtin_amdgcn_global_load_lds(AS1(gk), AS3(kqb + j), 16, 0, 0);
      }
      {
        int d = (j >> 7) + (l >> 3);
        int cc = l & 7;
        const short* gv = Vp + (long)d * LKV + kv0 + ((cc ^ (d & 7)) * 8);
        __builtin_amdgcn_global_load_lds(AS1(gv), AS3(vtb + j), 16, 0, 0);
      }
    }
  };

  // preload Q fragments (pre-scaled): lane l supplies Q[q=ql][c=16w+8h+j]
  short8 qf[16];
#pragma unroll
  for (int w = 0; w < 16; ++w) {
    const float* p = Qp + w * 16 + h * 8;
    f32x4 f0 = *(const f32x4*)p, f1 = *(const f32x4*)(p + 4);
    short8 v;
#pragma unroll
    for (int j = 0; j < 4; ++j) { v[j] = f2bf(f0[j] * SCQ); v[4 + j] = f2bf(f1[j] * SCQ); }
    qf[w] = v;
  }

  f32x16 o[8] = {};          // O[32q x 256d] accumulator (8 d-tiles of 32)
  float m_r = -1e30f, l_r = 0.f;

  const int kv_lo = ch * (LKV / NCHUNK);
  const int NT = (LKV / NCHUNK) / 64;   // 32 tiles

  stage(0, kv_lo);

  for (int t = 0; t < NT; ++t) {
    if (t + 1 < NT) {
      stage((t + 1) & 1, kv_lo + (t + 1) * 64);
      asm volatile("s_waitcnt vmcnt(16)" ::: "memory");   // tile t landed; t+1's 16 in flight
    } else {
      asm volatile("s_waitcnt vmcnt(0)" ::: "memory");
    }
    __builtin_amdgcn_s_barrier();
    __builtin_amdgcn_sched_barrier(0);
    char* kq = lds + (t & 1) * 65536;
    char* vt = kq + 32768;

    // ---- QK^T both 32-kv subtiles: two independent MFMA chains, interleaved ----
    f32x16 sa = {}, sb = {};
    {
      const int krA = ql, krB = 32 + ql;
      const int baseA = krA * 512, swzA = (krA & 15) << 4;
      const int baseB = krB * 512, swzB = (krB & 15) << 4;
#pragma unroll
      for (int w = 0; w < 16; ++w) {
        short8 kfA = *(const short8*)(kq + ((baseA + w * 32 + h * 16) ^ swzA));
        sa = mfma32(kfA, qf[w], sa);
        short8 kfB = *(const short8*)(kq + ((baseB + w * 32 + h * 16) ^ swzB));
        sb = mfma32(kfB, qf[w], sb);
      }
    }

    // ---- one tree-max over both subtiles (depth 5) + single deferred rescale ----
    {
      float m8[8];
#pragma unroll
      for (int i = 0; i < 8; ++i)
        m8[i] = fmaxf(fmaxf(sa[i], sa[i + 8]), fmaxf(sb[i], sb[i + 8]));
      float m0 = fmaxf(fmaxf(m8[0], m8[1]), fmaxf(m8[2], m8[3]));
      float m1 = fmaxf(fmaxf(m8[4], m8[5]), fmaxf(m8[6], m8[7]));
      float pmax = fmaxf(m0, m1);
      pmax = fmaxf(pmax, __shfl_xor(pmax, 32));
      if (__any(pmax > m_r + 8.f)) {
        float mn = fmaxf(m_r, pmax);
        float alpha = exp2f(m_r - mn);
        m_r = mn;
        l_r *= alpha;
#pragma unroll
        for (int rr = 0; rr < 16; ++rr) {
          int src = ((rr & 3) + 8 * (rr >> 2) + 4 * h) + 32 * h;
          float ar = __shfl(alpha, src);
#pragma unroll
          for (int nn = 0; nn < 8; ++nn) o[nn][rr] *= ar;
        }
      }
    }

    // ---- exp2 + pack both subtiles (4 partial sums), row-sum, exchange ----
    unsigned wpkA[8], wpkB[8];
    {
      float rs0 = 0.f, rs1 = 0.f, rs2 = 0.f, rs3 = 0.f;
#pragma unroll
      for (int k = 0; k < 8; ++k) {
        float a0 = exp2f(sa[2 * k] - m_r);
        float a1 = exp2f(sa[2 * k + 1] - m_r);
        float b0 = exp2f(sb[2 * k] - m_r);
        float b1 = exp2f(sb[2 * k + 1] - m_r);
        rs0 += a0; rs1 += a1; rs2 += b0; rs3 += b1;
        wpkA[k] = cvt_pk_bf16(a0, a1);
        wpkB[k] = cvt_pk_bf16(b0, b1);
      }
      float rs = (rs0 + rs1) + (rs2 + rs3);
      rs += __shfl_xor(rs, 32);
      l_r += rs;
    }
    // exchange with lane^32 -> PV A-frags: A[m=q][k=16v+8h+j]
    short8 paA[2], paB[2];
#pragma unroll
    for (int v = 0; v < 2; ++v) {
      {
        unsigned a0 = wpkA[4 * v], a1 = wpkA[4 * v + 1];
        unsigned b0 = wpkA[4 * v + 2], b1 = wpkA[4 * v + 3];
        unsigned own0 = h ? b0 : a0, own1 = h ? b1 : a1;
        unsigned snd0 = h ? a0 : b0, snd1 = h ? a1 : b1;
        unsigned rcv0 = __shfl_xor((int)snd0, 32), rcv1 = __shfl_xor((int)snd1, 32);
        unsigned lo0 = h ? rcv0 : own0, lo1 = h ? rcv1 : own1;
        unsigned hi0 = h ? own0 : rcv0, hi1 = h ? own1 : rcv1;
        uint4v u = {lo0, lo1, hi0, hi1};
        paA[v] = *(short8*)&u;
      }
      {
        unsigned a0 = wpkB[4 * v], a1 = wpkB[4 * v + 1];
        unsigned b0 = wpkB[4 * v + 2], b1 = wpkB[4 * v + 3];
        unsigned own0 = h ? b0 : a0, own1 = h ? b1 : a1;
        unsigned snd0 = h ? a0 : b0, snd1 = h ? a1 : b1;
        unsigned rcv0 = __shfl_xor((int)snd0, 32), rcv1 = __shfl_xor((int)snd1, 32);
        unsigned lo0 = h ? rcv0 : own0, lo1 = h ? rcv1 : own1;
        unsigned hi0 = h ? own0 : rcv0, hi1 = h ? own1 : rcv1;
        uint4v u = {lo0, lo1, hi0, hi1};
        paB[v] = *(short8*)&u;
      }
    }

    // ---- O += P V' for both subtiles: 8 o-chains x 4 mfma (ILP) ----
#pragma unroll
    for (int nn = 0; nn < 8; ++nn) {
      const int d = 32 * nn + ql;
      const int dbase = d * 128, dswz = (d & 7) << 4;
      short8 bv0 = *(const short8*)(vt + ((dbase + 0 * 32 + 16 * h) ^ dswz));
      o[nn] = mfma32(paA[0], bv0, o[nn]);
      short8 bv1 = *(const short8*)(vt + ((dbase + 1 * 32 + 16 * h) ^ dswz));
      o[nn] = mfma32(paA[1], bv1, o[nn]);
      short8 bv2 = *(const short8*)(vt + ((dbase + 2 * 32 + 16 * h) ^ dswz));
      o[nn] = mfma32(paB[0], bv2, o[nn]);
      short8 bv3 = *(const short8*)(vt + ((dbase + 3 * 32 + 16 * h) ^ dswz));
      o[nn] = mfma32(paB[1], bv3, o[nn]);
    }

    asm volatile("s_waitcnt lgkmcnt(0)" ::: "memory");  // all LDS reads consumed
    __builtin_amdgcn_s_barrier();                        // buf safe to overwrite next iter
    __builtin_amdgcn_sched_barrier(0);
  }

  // epilogue: unnormalized partial O (f32) + per-row m,l
  const long rowb = (long)b * LQ + qrow0;
#pragma unroll
  for (int rr = 0; rr < 16; ++rr) {
    long grow = rowb + (rr & 3) + 8 * (rr >> 2) + 4 * h;
    float* dst = Opart + ((long)ch * ROWS + grow) * 256 + ql;
#pragma unroll
    for (int nn = 0; nn < 8; ++nn) dst[32 * nn] = o[nn][rr];
  }
  if (h == 0) {
    Mb[(long)ch * ROWS + rowb + ql] = m_r;
    Lb[(long)ch * ROWS + rowb + ql] = l_r;
  }
}

// ---------------- layernorm over rows of 256 ----------------
__global__ void __launch_bounds__(256) ln256(
    const float* in, float* outF, short* outB,
    const float* __restrict__ g, const float* __restrict__ be) {
  const int w = threadIdx.x >> 6, l = threadIdx.x & 63;
  const long row = (long)blockIdx.x * 4 + w;
  const float* p = in + row * 256 + l * 4;
  f32x4 x = *(const f32x4*)p;
  float s = x[0] + x[1] + x[2] + x[3];
  float s2 = x[0] * x[0] + x[1] * x[1] + x[2] * x[2] + x[3] * x[3];
#pragma unroll
  for (int mk = 1; mk < 64; mk <<= 1) { s += __shfl_xor(s, mk); s2 += __shfl_xor(s2, mk); }
  float mu = s * (1.f / 256.f);
  float var = s2 * (1.f / 256.f) - mu * mu;
  float rstd = rsqrtf(var + 1e-5f);
  f32x4 gg = *(const f32x4*)(g + l * 4);
  f32x4 bb = *(const f32x4*)(be + l * 4);
  f32x4 y;
#pragma unroll
  for (int k = 0; k < 4; ++k) y[k] = (x[k] - mu) * rstd * gg[k] + bb[k];
  if (outF) *(f32x4*)(outF + row * 256 + l * 4) = y;
  if (outB) {
    short4v yb;
#pragma unroll
    for (int k = 0; k < 4; ++k) yb[k] = f2bf(y[k]);
    *(short4v*)(outB + row * 256 + l * 4) = yb;
  }
}

// ---------------- launcher ----------------
extern "C" void kernel_launch(void* const* d_in, const int* in_sizes, int n_in,
                              void* d_out, int out_size, void* d_ws, size_t ws_size,
                              hipStream_t stream) {
  const float* query = (const float*)d_in[0];
  const float* key   = (const float*)d_in[1];
  const float* value = (const float*)d_in[2];
  const float* Wk  = (const float*)d_in[3];
  const float* bk  = (const float*)d_in[4];
  const float* Wv  = (const float*)d_in[5];
  const float* bv  = (const float*)d_in[6];
  const float* Wo  = (const float*)d_in[7];
  const float* bo  = (const float*)d_in[8];
  const float* g1  = (const float*)d_in[9];
  const float* b1  = (const float*)d_in[10];
  const float* g2  = (const float*)d_in[11];
  const float* b2  = (const float*)d_in[12];
  const float* W1  = (const float*)d_in[13];
  const float* bf1 = (const float*)d_in[14];
  const float* W2  = (const float*)d_in[15];
  const float* bf2 = (const float*)d_in[16];

  char* ws = (char*)d_ws;
  size_t off = 0;
  auto take = [&](size_t bytes) { char* p = ws + off; off += bytes; return p; };
  short* WkT = (short*)take((size_t)256 * 256 * 2);
  short* WvT = (short*)take((size_t)256 * 256 * 2);
  short* WoT = (short*)take((size_t)256 * 256 * 2);
  short* W1T = (short*)take((size_t)1024 * 256 * 2);
  short* W2T = (short*)take((size_t)256 * 1024 * 2);
  short* Kb  = (short*)take((size_t)NB * LKV * DQ * 2);   // dead after flash -> Hb aliases
  short* Vt  = (short*)take((size_t)NB * DQ * LKV * 2);
  float* Opart = (float*)take((size_t)NCHUNK * ROWS * 256 * 4);  // dead after Wo -> Xb aliases
  float* Mbuf  = (float*)take((size_t)NCHUNK * ROWS * 4);
  float* Lbuf  = (float*)take((size_t)NCHUNK * ROWS * 4);
  float* Xf    = (float*)take((size_t)ROWS * 256 * 4);
  short* Xb  = (short*)Opart;            // LN1 bf16 out (Opart dead)
  short* Hb  = (short*)Kb;               // FF1 out 33.6MB = Kb+Vt region (dead)
  (void)ws_size; (void)in_sizes; (void)n_in; (void)out_size;

  dim3 blk(256);
  dim3 tb(32, 8);
  transpose_cast<<<dim3(8, 8),  tb, 0, stream>>>(Wk, WkT, 256, 256);
  transpose_cast<<<dim3(8, 8),  tb, 0, stream>>>(Wv, WvT, 256, 256);
  transpose_cast<<<dim3(8, 8),  tb, 0, stream>>>(Wo, WoT, 256, 256);
  transpose_cast<<<dim3(32, 8), tb, 0, stream>>>(W1, W1T, 256, 1024);
  transpose_cast<<<dim3(8, 32), tb, 0, stream>>>(W2, W2T, 1024, 256);

  // K' = key @ Wk + bk   -> Kb [B*LKV][256] bf16   (A: f32 reg, B: bf16 gload)
  gemm128<1, 0, 0><<<dim3(2, 256, 1), blk, 0, stream>>>(
      key, 0, 256, WkT, 0, 256, bk, nullptr, 0, nullptr, nullptr, Kb, 0, 256, 256);
  // V'^T = (value @ Wv + bv)^T -> Vt [B][256][LKV] bf16  (A = WvT gload, B = value f32)
  gemm128<0, 1, 1><<<dim3(32, 2, 8), blk, 0, stream>>>(
      WvT, 0, 256, value, (long)LKV * 256, 256, bv, nullptr, 0, nullptr, nullptr,
      Vt, (long)256 * LKV, LKV, 256);
  // attention (KV-split 2, swapped-QK^T 32x32, batched subtiles, dbuf, XCD-pinned)
  flash_attn<<<dim3(256), blk, 0, stream>>>(query, Kb, Vt, Opart, Mbuf, Lbuf);
  // attn_out = combine(Opart) @ Wo + bo + query -> Xf f32   (combine fused in A-stage)
  gemm128<2, 0, 2><<<dim3(2, 128, 1), blk, 0, stream>>>(
      Opart, 0, 256, WoT, 0, 256, bo, query, 0, Mbuf, Lbuf, Xf, 0, 256, 256);
  // x = LN1(Xf) -> Xf (f32, in-place) + Xb (bf16)
  ln256<<<4096, blk, 0, stream>>>(Xf, Xf, Xb, g1, b1);
  // h = relu(x @ W1 + bf1) -> Hb bf16  (both operands gload)
  gemm128<0, 0, 3><<<dim3(8, 128, 1), blk, 0, stream>>>(
      Xb, 0, 256, W1T, 0, 256, bf1, nullptr, 0, nullptr, nullptr, Hb, 0, 1024, 256);
  // y = h @ W2 + bf2 + x -> Xf (in-place)
  gemm128<0, 0, 2><<<dim3(2, 128, 1), blk, 0, stream>>>(
      Hb, 0, 1024, W2T, 0, 1024, bf2, Xf, 0, nullptr, nullptr, Xf, 0, 256, 1024);
  // out = LN2(Xf)
  ln256<<<4096, blk, 0, stream>>>(Xf, (float*)d_out, nullptr, g2, b2);
}